// Round 4
// baseline (1666.119 us; speedup 1.0000x reference)
//
#include <hip/hip_runtime.h>
#include <math.h>

#define NN 100000
#define NE 1600000
#define NG 64

__device__ __forceinline__ float gelu_f(float x) {
    return 0.5f * x * (1.0f + erff(x * 0.7071067811865475f));
}

// ---------------- CSR build ----------------
__global__ void k_hist(const int* __restrict__ dstp, int* __restrict__ cnt) {
    int e = blockIdx.x * 256 + threadIdx.x;
    if (e < NE) atomicAdd(&cnt[dstp[e]], 1);
}

#define SB 1024
__global__ __launch_bounds__(SB) void k_scan1(const int* __restrict__ cnt, int* __restrict__ rowp,
                                              int* __restrict__ blksum) {
    __shared__ int s[SB];
    int tid = threadIdx.x;
    int i = blockIdx.x * SB + tid;
    int v = (i < NN) ? cnt[i] : 0;
    int run = v;
    s[tid] = v;
    __syncthreads();
    for (int off = 1; off < SB; off <<= 1) {
        int t = (tid >= off) ? s[tid - off] : 0;
        __syncthreads();
        run += t;
        s[tid] = run;
        __syncthreads();
    }
    if (i < NN) rowp[i] = run - v;            // exclusive within block
    if (tid == SB - 1) blksum[blockIdx.x] = run;
}

__global__ void k_scan2(const int* __restrict__ blksum, int* __restrict__ blkoff, int nb) {
    __shared__ int s[128];
    int tid = threadIdx.x;
    int v = (tid < nb) ? blksum[tid] : 0;
    int run = v;
    s[tid] = v;
    __syncthreads();
    for (int off = 1; off < 128; off <<= 1) {
        int t = (tid >= off) ? s[tid - off] : 0;
        __syncthreads();
        run += t;
        s[tid] = run;
        __syncthreads();
    }
    if (tid < nb) blkoff[tid] = run - v;
}

__global__ void k_scan3(int* __restrict__ rowp, const int* __restrict__ blkoff) {
    int i = blockIdx.x * 256 + threadIdx.x;
    if (i < NN) rowp[i] += blkoff[i >> 10];
    else if (i == NN) rowp[NN] = NE;
}

__global__ void k_scatter(const int* __restrict__ srcp, const int* __restrict__ dstp,
                          const int* __restrict__ rowp, int* __restrict__ fill,
                          int* __restrict__ cidx) {
    int e = blockIdx.x * 256 + threadIdx.x;
    if (e < NE) {
        int d = dstp[e];
        int pos = atomicAdd(&fill[d], 1);
        cidx[rowp[d] + pos] = srcp[e];
    }
}

// ---------------- mean-aggregate: 32 lanes x float4 per node, 8 edges in flight ----------------
__global__ __launch_bounds__(256) void k_agg(const float* __restrict__ xin, const int* __restrict__ rowp,
                                             const int* __restrict__ cidx, float* __restrict__ agg) {
    int tid = blockIdx.x * 256 + threadIdx.x;
    int node = tid >> 5;
    int lane = tid & 31;
    if (node >= NN) return;
    int beg = rowp[node], endp = rowp[node + 1];
    const float4* x4 = (const float4*)xin;
    float sx = 0.f, sy = 0.f, sz = 0.f, sw = 0.f;
    int e = beg;
    for (; e + 7 < endp; e += 8) {
        int i0 = cidx[e],     i1 = cidx[e + 1], i2 = cidx[e + 2], i3 = cidx[e + 3];
        int i4 = cidx[e + 4], i5 = cidx[e + 5], i6 = cidx[e + 6], i7 = cidx[e + 7];
        float4 v0 = x4[(size_t)i0 * 32 + lane];
        float4 v1 = x4[(size_t)i1 * 32 + lane];
        float4 v2 = x4[(size_t)i2 * 32 + lane];
        float4 v3 = x4[(size_t)i3 * 32 + lane];
        float4 v4 = x4[(size_t)i4 * 32 + lane];
        float4 v5 = x4[(size_t)i5 * 32 + lane];
        float4 v6 = x4[(size_t)i6 * 32 + lane];
        float4 v7 = x4[(size_t)i7 * 32 + lane];
        sx += ((v0.x + v1.x) + (v2.x + v3.x)) + ((v4.x + v5.x) + (v6.x + v7.x));
        sy += ((v0.y + v1.y) + (v2.y + v3.y)) + ((v4.y + v5.y) + (v6.y + v7.y));
        sz += ((v0.z + v1.z) + (v2.z + v3.z)) + ((v4.z + v5.z) + (v6.z + v7.z));
        sw += ((v0.w + v1.w) + (v2.w + v3.w)) + ((v4.w + v5.w) + (v6.w + v7.w));
    }
    for (; e + 3 < endp; e += 4) {
        int i0 = cidx[e], i1 = cidx[e + 1], i2 = cidx[e + 2], i3 = cidx[e + 3];
        float4 v0 = x4[(size_t)i0 * 32 + lane];
        float4 v1 = x4[(size_t)i1 * 32 + lane];
        float4 v2 = x4[(size_t)i2 * 32 + lane];
        float4 v3 = x4[(size_t)i3 * 32 + lane];
        sx += (v0.x + v1.x) + (v2.x + v3.x);
        sy += (v0.y + v1.y) + (v2.y + v3.y);
        sz += (v0.z + v1.z) + (v2.z + v3.z);
        sw += (v0.w + v1.w) + (v2.w + v3.w);
    }
    for (; e < endp; ++e) {
        int i0 = cidx[e];
        float4 v0 = x4[(size_t)i0 * 32 + lane];
        sx += v0.x; sy += v0.y; sz += v0.z; sw += v0.w;
    }
    float inv = 1.0f / fmaxf((float)(endp - beg), 1.0f);
    float4 r;
    r.x = sx * inv; r.y = sy * inv; r.z = sz * inv; r.w = sw * inv;
    ((float4*)agg)[(size_t)node * 32 + lane] = r;
}

// ---------------- fused SAGE layer: out = gelu(A1@W1 + b1 + A2@W2) ----------------
// 256 threads; tile = 128 nodes x 128 cols; thread = 8 nodes x 8 cols.
// Thread cols split as {cg*4..+3} and {64+cg*4..+3}: each ds_read_b128 has the
// 16 cg-lanes at 16B stride (contiguous 256B, 2 lanes/bank = conflict-free).
// W1,W2 staged in 32KB LDS as 32-row k-quarters -> up to 5 blocks/CU.
// In-place safety (out may alias A1): each node row is read/written ONLY by the 16
// consecutive threads (same wave) owning it; wave lockstep orders k-loop loads
// before epilogue stores. Clamped tail reads are discarded.
__global__ __launch_bounds__(256, 4) void k_sage(const float* A1, const float* __restrict__ W1,
                                                 const float* __restrict__ b1, const float* A2,
                                                 const float* __restrict__ W2, float* out) {
    __shared__ float ws[8192];  // [0..4095]: W1 quarter [32][128]; [4096..]: W2 quarter
    const int t = threadIdx.x;
    const int cg = t & 15;
    const int ng = t >> 4;
    const int n0 = blockIdx.x * 128 + ng * 8;
    const int c0a = cg * 4;
    const int c0b = 64 + cg * 4;
    float acc[8][8];
#pragma unroll
    for (int i = 0; i < 8; ++i)
#pragma unroll
        for (int j = 0; j < 8; ++j) acc[i][j] = 0.f;
    const float *r1[8], *r2[8];
#pragma unroll
    for (int i = 0; i < 8; ++i) {
        int n = n0 + i;
        if (n >= NN) n = NN - 1;  // clamp loads; stores guarded below
        r1[i] = A1 + (size_t)n * 128;
        r2[i] = A2 + (size_t)n * 128;
    }
    for (int kb = 0; kb < 128; kb += 32) {
        __syncthreads();  // previous quarter fully consumed before overwrite
        {
            const float4* w1q = (const float4*)(W1 + kb * 128);
            const float4* w2q = (const float4*)(W2 + kb * 128);
#pragma unroll
            for (int u = 0; u < 4; ++u) {
                int idx = t + u * 256;  // 1024 float4 per matrix quarter
                ((float4*)ws)[idx] = w1q[idx];
                ((float4*)(ws + 4096))[idx] = w2q[idx];
            }
        }
        __syncthreads();
        for (int k2 = 0; k2 < 32; k2 += 4) {
            const int k = kb + k2;
            float w1v[4][8], w2v[4][8];
#pragma unroll
            for (int kk = 0; kk < 4; ++kk) {
                *(float4*)&w1v[kk][0] = *(const float4*)&ws[(k2 + kk) * 128 + c0a];
                *(float4*)&w1v[kk][4] = *(const float4*)&ws[(k2 + kk) * 128 + c0b];
                *(float4*)&w2v[kk][0] = *(const float4*)&ws[4096 + (k2 + kk) * 128 + c0a];
                *(float4*)&w2v[kk][4] = *(const float4*)&ws[4096 + (k2 + kk) * 128 + c0b];
            }
#pragma unroll
            for (int h = 0; h < 2; ++h) {
                float4 a1[4], a2[4];
#pragma unroll
                for (int i = 0; i < 4; ++i) {
                    a1[i] = *(const float4*)(r1[h * 4 + i] + k);
                    a2[i] = *(const float4*)(r2[h * 4 + i] + k);
                }
#pragma unroll
                for (int i = 0; i < 4; ++i) {
#pragma unroll
                    for (int kk = 0; kk < 4; ++kk) {
                        float x1 = (kk == 0) ? a1[i].x : (kk == 1) ? a1[i].y : (kk == 2) ? a1[i].z : a1[i].w;
                        float x2 = (kk == 0) ? a2[i].x : (kk == 1) ? a2[i].y : (kk == 2) ? a2[i].z : a2[i].w;
#pragma unroll
                        for (int j = 0; j < 8; ++j)
                            acc[h * 4 + i][j] = fmaf(x1, w1v[kk][j], fmaf(x2, w2v[kk][j], acc[h * 4 + i][j]));
                    }
                }
            }
        }
    }
    float bv[8];
    *(float4*)&bv[0] = *(const float4*)(b1 + c0a);
    *(float4*)&bv[4] = *(const float4*)(b1 + c0b);
#pragma unroll
    for (int i = 0; i < 8; ++i) {
        int n = n0 + i;
        if (n < NN) {
            float* orow = out + (size_t)n * 128;
            float4 v;
            v.x = gelu_f(acc[i][0] + bv[0]);
            v.y = gelu_f(acc[i][1] + bv[1]);
            v.z = gelu_f(acc[i][2] + bv[2]);
            v.w = gelu_f(acc[i][3] + bv[3]);
            *(float4*)(orow + c0a) = v;
            v.x = gelu_f(acc[i][4] + bv[4]);
            v.y = gelu_f(acc[i][5] + bv[5]);
            v.z = gelu_f(acc[i][6] + bv[6]);
            v.w = gelu_f(acc[i][7] + bv[7]);
            *(float4*)(orow + c0b) = v;
        }
    }
}

// ---------------- fused gate: gate[n] = gelu(H@Wg1+bg1) . Wg2   (bg2 dropped:
// per-graph softmax is invariant to a constant shift of the scores) ----------------
__global__ __launch_bounds__(256, 4) void k_gatef(const float* __restrict__ H, const float* __restrict__ Wg1,
                                                  const float* __restrict__ bg1, const float* __restrict__ Wg2,
                                                  float* __restrict__ gate) {
    __shared__ float ws[4096];  // Wg1 quarter [32][128] = 16KB
    const int t = threadIdx.x;
    const int cg = t & 15;
    const int ng = t >> 4;
    const int n0 = blockIdx.x * 128 + ng * 8;
    const int c0a = cg * 4;
    const int c0b = 64 + cg * 4;
    float acc[8][8];
#pragma unroll
    for (int i = 0; i < 8; ++i)
#pragma unroll
        for (int j = 0; j < 8; ++j) acc[i][j] = 0.f;
    const float* r1[8];
#pragma unroll
    for (int i = 0; i < 8; ++i) {
        int n = n0 + i;
        if (n >= NN) n = NN - 1;
        r1[i] = H + (size_t)n * 128;
    }
    for (int kb = 0; kb < 128; kb += 32) {
        __syncthreads();
        {
            const float4* wq = (const float4*)(Wg1 + kb * 128);
#pragma unroll
            for (int u = 0; u < 4; ++u) {
                int idx = t + u * 256;
                ((float4*)ws)[idx] = wq[idx];
            }
        }
        __syncthreads();
        for (int k2 = 0; k2 < 32; k2 += 4) {
            const int k = kb + k2;
            float w1v[4][8];
#pragma unroll
            for (int kk = 0; kk < 4; ++kk) {
                *(float4*)&w1v[kk][0] = *(const float4*)&ws[(k2 + kk) * 128 + c0a];
                *(float4*)&w1v[kk][4] = *(const float4*)&ws[(k2 + kk) * 128 + c0b];
            }
#pragma unroll
            for (int h = 0; h < 2; ++h) {
                float4 a1[4];
#pragma unroll
                for (int i = 0; i < 4; ++i) a1[i] = *(const float4*)(r1[h * 4 + i] + k);
#pragma unroll
                for (int i = 0; i < 4; ++i) {
#pragma unroll
                    for (int kk = 0; kk < 4; ++kk) {
                        float x1 = (kk == 0) ? a1[i].x : (kk == 1) ? a1[i].y : (kk == 2) ? a1[i].z : a1[i].w;
#pragma unroll
                        for (int j = 0; j < 8; ++j)
                            acc[h * 4 + i][j] = fmaf(x1, w1v[kk][j], acc[h * 4 + i][j]);
                    }
                }
            }
        }
    }
    float bv[8], gv[8];
    *(float4*)&bv[0] = *(const float4*)(bg1 + c0a);
    *(float4*)&bv[4] = *(const float4*)(bg1 + c0b);
    *(float4*)&gv[0] = *(const float4*)(Wg2 + c0a);
    *(float4*)&gv[4] = *(const float4*)(Wg2 + c0b);
    float part[8];
#pragma unroll
    for (int i = 0; i < 8; ++i) {
        float p = 0.f;
#pragma unroll
        for (int j = 0; j < 8; ++j) p += gelu_f(acc[i][j] + bv[j]) * gv[j];
        part[i] = p;
    }
#pragma unroll
    for (int m = 1; m < 16; m <<= 1) {
#pragma unroll
        for (int i = 0; i < 8; ++i) part[i] += __shfl_xor(part[i], m);
    }
    if (cg == 0) {
#pragma unroll
        for (int i = 0; i < 8; ++i) {
            int n = n0 + i;
            if (n < NN) gate[n] = part[i];
        }
    }
}

// ---------------- pooling stage 1: per-graph max + exp-sum over gate ----------------
__global__ __launch_bounds__(256) void k_pstats(const float* __restrict__ gate, const int* __restrict__ batch,
                                                float* __restrict__ gm, float* __restrict__ gden) {
    int g = blockIdx.x;
    int lo = 0, hi = NN;
    while (lo < hi) { int mid = (lo + hi) >> 1; if (batch[mid] < g) lo = mid + 1; else hi = mid; }
    int start = lo;
    lo = start; hi = NN;
    while (lo < hi) { int mid = (lo + hi) >> 1; if (batch[mid] < g + 1) lo = mid + 1; else hi = mid; }
    int endp = lo;

    __shared__ float red[256];
    int tid = threadIdx.x;

    float m = -1e30f;
    for (int i = start + tid; i < endp; i += 256) m = fmaxf(m, gate[i]);
    red[tid] = m;
    __syncthreads();
    for (int off = 128; off; off >>= 1) {
        if (tid < off) red[tid] = fmaxf(red[tid], red[tid + off]);
        __syncthreads();
    }
    m = red[0];
    __syncthreads();

    float s = 0.f;
    for (int i = start + tid; i < endp; i += 256) s += expf(gate[i] - m);
    red[tid] = s;
    __syncthreads();
    for (int off = 128; off; off >>= 1) {
        if (tid < off) red[tid] += red[tid + off];
        __syncthreads();
    }
    if (tid == 0) { gm[g] = m; gden[g] = red[0]; }
}

// ---------------- pooling stage 2: node-parallel weighted accumulate ----------------
// 128-node tile per block; 2 threads per column. Sorted batch -> register-run
// accumulation, one atomicAdd per (graph-run, thread).
__global__ __launch_bounds__(256) void k_pacc(const float* __restrict__ H, const float* __restrict__ gate,
                                              const int* __restrict__ batch, const float* __restrict__ gm,
                                              const float* __restrict__ gden, float* __restrict__ gacc) {
    int c = threadIdx.x & 127;
    int h = threadIdx.x >> 7;
    int n0 = blockIdx.x * 128;
    int nend = n0 + 128;
    if (nend > NN) nend = NN;
    int i = n0 + h;
    if (i >= nend) return;
    int cur = batch[i];
    float m = gm[cur], invd = 1.0f / gden[cur];
    float acc = 0.f;
    for (; i < nend; i += 2) {
        int gi = batch[i];
        if (gi != cur) {
            atomicAdd(&gacc[cur * 128 + c], acc * invd);
            acc = 0.f;
            cur = gi;
            m = gm[cur];
            invd = 1.0f / gden[cur];
        }
        acc = fmaf(expf(gate[i] - m), H[(size_t)i * 128 + c], acc);
    }
    atomicAdd(&gacc[cur * 128 + c], acc * invd);
}

// ---------------- head: out[g] = g . Wh + bh ----------------
__global__ __launch_bounds__(64) void k_head(const float* __restrict__ gacc, const float* __restrict__ Wh,
                                             const float* __restrict__ bh, float* __restrict__ out) {
    int g = blockIdx.x;
    int l = threadIdx.x;
    float v = gacc[g * 128 + l] * Wh[l] + gacc[g * 128 + 64 + l] * Wh[64 + l];
#pragma unroll
    for (int m = 1; m < 64; m <<= 1) v += __shfl_xor(v, m);
    if (l == 0) out[g] = v + bh[0];
}

extern "C" void kernel_launch(void* const* d_in, const int* in_sizes, int n_in,
                              void* d_out, int out_size, void* d_ws, size_t ws_size,
                              hipStream_t stream) {
    (void)in_sizes; (void)n_in; (void)out_size; (void)ws_size;
    const float* x   = (const float*)d_in[0];
    const int*  ei   = (const int*)d_in[1];
    const int*  batch= (const int*)d_in[2];
    const float* Wl0 = (const float*)d_in[3];
    const float* bl0 = (const float*)d_in[4];
    const float* Wr0 = (const float*)d_in[5];
    const float* Wl1 = (const float*)d_in[6];
    const float* bl1 = (const float*)d_in[7];
    const float* Wr1 = (const float*)d_in[8];
    const float* Wg1 = (const float*)d_in[9];
    const float* bg1 = (const float*)d_in[10];
    const float* Wg2 = (const float*)d_in[11];
    const float* Wh  = (const float*)d_in[13];
    const float* bh  = (const float*)d_in[14];
    float* out = (float*)d_out;

    const int* srcp = ei;
    const int* dstp = ei + NE;

    char* w = (char*)d_ws;
    size_t off = 0;
    auto alloc = [&](size_t bytes) { void* p = w + off; off += (bytes + 255) & ~(size_t)255; return p; };
    float* bufA  = (float*)alloc((size_t)NN * 128 * 4);  // agg / h2
    float* bufH  = (float*)alloc((size_t)NN * 128 * 4);  // h1
    float* gate  = (float*)alloc((size_t)NN * 4);
    int* cnt     = (int*)alloc((size_t)NN * 4);
    int* rowp    = (int*)alloc((size_t)(NN + 1) * 4);
    int* fill    = (int*)alloc((size_t)NN * 4);
    int* cidx    = (int*)alloc((size_t)NE * 4);
    int* blksum  = (int*)alloc(128 * 4);
    int* blkoff  = (int*)alloc(128 * 4);
    float* gm    = (float*)alloc(NG * 4);
    float* gden  = (float*)alloc(NG * 4);
    float* gacc  = (float*)alloc((size_t)NG * 128 * 4);

    hipMemsetAsync(cnt, 0, (size_t)NN * 4, stream);
    hipMemsetAsync(fill, 0, (size_t)NN * 4, stream);
    hipMemsetAsync(gacc, 0, (size_t)NG * 128 * 4, stream);

    // CSR build (reused by both layers)
    k_hist<<<(NE + 255) / 256, 256, 0, stream>>>(dstp, cnt);
    int nb = (NN + SB - 1) / SB;
    k_scan1<<<nb, SB, 0, stream>>>(cnt, rowp, blksum);
    k_scan2<<<1, 128, 0, stream>>>(blksum, blkoff, nb);
    k_scan3<<<(NN + 1 + 255) / 256, 256, 0, stream>>>(rowp, blkoff);
    k_scatter<<<(NE + 255) / 256, 256, 0, stream>>>(srcp, dstp, rowp, fill, cidx);

    int gs = (NN + 127) / 128;           // 256-thread GEMM blocks (128-node tiles)
    int ga = (NN * 32 + 255) / 256;      // k_agg: 32 lanes per node
    // layer 0
    k_agg<<<ga, 256, 0, stream>>>(x, rowp, cidx, bufA);
    k_sage<<<gs, 256, 0, stream>>>(bufA, Wl0, bl0, x, Wr0, bufH);      // h1
    // layer 1
    k_agg<<<ga, 256, 0, stream>>>(bufH, rowp, cidx, bufA);
    k_sage<<<gs, 256, 0, stream>>>(bufA, Wl1, bl1, bufH, Wr1, bufA);   // h2 in-place (wave-owned rows)
    // gate + pool + head
    k_gatef<<<gs, 256, 0, stream>>>(bufA, Wg1, bg1, Wg2, gate);
    k_pstats<<<NG, 256, 0, stream>>>(gate, batch, gm, gden);
    k_pacc<<<(NN + 127) / 128, 256, 0, stream>>>(bufA, gate, batch, gm, gden, gacc);
    k_head<<<NG, 64, 0, stream>>>(gacc, Wh, bh, out);
}

// Round 5
// 770.057 us; speedup vs baseline: 2.1636x; 2.1636x over previous
//
#include <hip/hip_runtime.h>
#include <math.h>

#define NN 100000
#define NE 1600000
#define NG 64

__device__ __forceinline__ float gelu_f(float x) {
    return 0.5f * x * (1.0f + erff(x * 0.7071067811865475f));
}

// ---------------- CSR build ----------------
__global__ void k_hist(const int* __restrict__ dstp, int* __restrict__ cnt) {
    int e = blockIdx.x * 256 + threadIdx.x;
    if (e < NE) atomicAdd(&cnt[dstp[e]], 1);
}

#define SB 1024
__global__ __launch_bounds__(SB) void k_scan1(const int* __restrict__ cnt, int* __restrict__ rowp,
                                              int* __restrict__ blksum) {
    __shared__ int s[SB];
    int tid = threadIdx.x;
    int i = blockIdx.x * SB + tid;
    int v = (i < NN) ? cnt[i] : 0;
    int run = v;
    s[tid] = v;
    __syncthreads();
    for (int off = 1; off < SB; off <<= 1) {
        int t = (tid >= off) ? s[tid - off] : 0;
        __syncthreads();
        run += t;
        s[tid] = run;
        __syncthreads();
    }
    if (i < NN) rowp[i] = run - v;            // exclusive within block
    if (tid == SB - 1) blksum[blockIdx.x] = run;
}

__global__ void k_scan2(const int* __restrict__ blksum, int* __restrict__ blkoff, int nb) {
    __shared__ int s[128];
    int tid = threadIdx.x;
    int v = (tid < nb) ? blksum[tid] : 0;
    int run = v;
    s[tid] = v;
    __syncthreads();
    for (int off = 1; off < 128; off <<= 1) {
        int t = (tid >= off) ? s[tid - off] : 0;
        __syncthreads();
        run += t;
        s[tid] = run;
        __syncthreads();
    }
    if (tid < nb) blkoff[tid] = run - v;
}

__global__ void k_scan3(int* __restrict__ rowp, const int* __restrict__ blkoff) {
    int i = blockIdx.x * 256 + threadIdx.x;
    if (i < NN) rowp[i] += blkoff[i >> 10];
    else if (i == NN) rowp[NN] = NE;
}

__global__ void k_scatter(const int* __restrict__ srcp, const int* __restrict__ dstp,
                          const int* __restrict__ rowp, int* __restrict__ fill,
                          int* __restrict__ cidx) {
    int e = blockIdx.x * 256 + threadIdx.x;
    if (e < NE) {
        int d = dstp[e];
        int pos = atomicAdd(&fill[d], 1);
        cidx[rowp[d] + pos] = srcp[e];
    }
}

// ---------------- mean-aggregate: 32 lanes x float4 per node, 8 edges in flight ----------------
__global__ __launch_bounds__(256) void k_agg(const float* __restrict__ xin, const int* __restrict__ rowp,
                                             const int* __restrict__ cidx, float* __restrict__ agg) {
    int tid = blockIdx.x * 256 + threadIdx.x;
    int node = tid >> 5;
    int lane = tid & 31;
    if (node >= NN) return;
    int beg = rowp[node], endp = rowp[node + 1];
    const float4* x4 = (const float4*)xin;
    float sx = 0.f, sy = 0.f, sz = 0.f, sw = 0.f;
    int e = beg;
    for (; e + 7 < endp; e += 8) {
        int i0 = cidx[e],     i1 = cidx[e + 1], i2 = cidx[e + 2], i3 = cidx[e + 3];
        int i4 = cidx[e + 4], i5 = cidx[e + 5], i6 = cidx[e + 6], i7 = cidx[e + 7];
        float4 v0 = x4[(size_t)i0 * 32 + lane];
        float4 v1 = x4[(size_t)i1 * 32 + lane];
        float4 v2 = x4[(size_t)i2 * 32 + lane];
        float4 v3 = x4[(size_t)i3 * 32 + lane];
        float4 v4 = x4[(size_t)i4 * 32 + lane];
        float4 v5 = x4[(size_t)i5 * 32 + lane];
        float4 v6 = x4[(size_t)i6 * 32 + lane];
        float4 v7 = x4[(size_t)i7 * 32 + lane];
        sx += ((v0.x + v1.x) + (v2.x + v3.x)) + ((v4.x + v5.x) + (v6.x + v7.x));
        sy += ((v0.y + v1.y) + (v2.y + v3.y)) + ((v4.y + v5.y) + (v6.y + v7.y));
        sz += ((v0.z + v1.z) + (v2.z + v3.z)) + ((v4.z + v5.z) + (v6.z + v7.z));
        sw += ((v0.w + v1.w) + (v2.w + v3.w)) + ((v4.w + v5.w) + (v6.w + v7.w));
    }
    for (; e + 3 < endp; e += 4) {
        int i0 = cidx[e], i1 = cidx[e + 1], i2 = cidx[e + 2], i3 = cidx[e + 3];
        float4 v0 = x4[(size_t)i0 * 32 + lane];
        float4 v1 = x4[(size_t)i1 * 32 + lane];
        float4 v2 = x4[(size_t)i2 * 32 + lane];
        float4 v3 = x4[(size_t)i3 * 32 + lane];
        sx += (v0.x + v1.x) + (v2.x + v3.x);
        sy += (v0.y + v1.y) + (v2.y + v3.y);
        sz += (v0.z + v1.z) + (v2.z + v3.z);
        sw += (v0.w + v1.w) + (v2.w + v3.w);
    }
    for (; e < endp; ++e) {
        int i0 = cidx[e];
        float4 v0 = x4[(size_t)i0 * 32 + lane];
        sx += v0.x; sy += v0.y; sz += v0.z; sw += v0.w;
    }
    float inv = 1.0f / fmaxf((float)(endp - beg), 1.0f);
    float4 r;
    r.x = sx * inv; r.y = sy * inv; r.z = sz * inv; r.w = sw * inv;
    ((float4*)agg)[(size_t)node * 32 + lane] = r;
}

// ---------------- fused SAGE layer: out = gelu(A1@W1 + b1 + A2@W2) ----------------
// 512 threads; tile = 256 nodes x 128 cols; thread = 8 nodes x 8 cols.
// Thread cols split as {cg*4..+3} and {64+cg*4..+3}: each ds_read_b128 spans a
// contiguous 256B across the 16 cg-lanes (2 lanes/bank = conflict-free), vs the
// old cg*8 layout (32B stride = 4-way bank conflict, 6.4M conflict cycles).
// W1,W2 staged in 64KB LDS in two 64-row k-halves; launch_bounds(512,2) keeps
// the VGPR cap at 256 (round-4's (256,4) cap forced accumulator spills).
// In-place safety (out may alias A1): each node row is read/written ONLY by the 16
// consecutive threads (same wave) owning it; wave lockstep orders k-loop loads
// before epilogue stores. Clamped tail reads are discarded.
__global__ __launch_bounds__(512, 2) void k_sage(const float* A1, const float* __restrict__ W1,
                                                 const float* __restrict__ b1, const float* A2,
                                                 const float* __restrict__ W2, float* out) {
    __shared__ float ws[16384];  // [0..8191]: W1 k-half [64][128]; [8192..]: W2 k-half
    const int t = threadIdx.x;
    const int cg = t & 15;
    const int ng = t >> 4;
    const int n0 = blockIdx.x * 256 + ng * 8;
    const int c0a = cg * 4;
    const int c0b = 64 + cg * 4;
    float acc[8][8];
#pragma unroll
    for (int i = 0; i < 8; ++i)
#pragma unroll
        for (int j = 0; j < 8; ++j) acc[i][j] = 0.f;
    const float *r1[8], *r2[8];
#pragma unroll
    for (int i = 0; i < 8; ++i) {
        int n = n0 + i;
        if (n >= NN) n = NN - 1;  // clamp loads; stores guarded below
        r1[i] = A1 + (size_t)n * 128;
        r2[i] = A2 + (size_t)n * 128;
    }
    for (int kb = 0; kb < 128; kb += 64) {
        __syncthreads();  // previous half fully consumed before overwrite
        for (int idx = t; idx < 2048; idx += 512) {  // 64 rows x 32 float4-chunks
            ((float4*)ws)[idx]        = ((const float4*)(W1 + kb * 128))[idx];
            ((float4*)ws)[2048 + idx] = ((const float4*)(W2 + kb * 128))[idx];
        }
        __syncthreads();
        for (int k2 = 0; k2 < 64; k2 += 4) {
            const int k = kb + k2;
            float w1v[4][8], w2v[4][8];
#pragma unroll
            for (int kk = 0; kk < 4; ++kk) {
                *(float4*)&w1v[kk][0] = *(const float4*)&ws[(k2 + kk) * 128 + c0a];
                *(float4*)&w1v[kk][4] = *(const float4*)&ws[(k2 + kk) * 128 + c0b];
                *(float4*)&w2v[kk][0] = *(const float4*)&ws[8192 + (k2 + kk) * 128 + c0a];
                *(float4*)&w2v[kk][4] = *(const float4*)&ws[8192 + (k2 + kk) * 128 + c0b];
            }
#pragma unroll
            for (int h = 0; h < 2; ++h) {
                float4 a1[4], a2[4];
#pragma unroll
                for (int i = 0; i < 4; ++i) {
                    a1[i] = *(const float4*)(r1[h * 4 + i] + k);
                    a2[i] = *(const float4*)(r2[h * 4 + i] + k);
                }
#pragma unroll
                for (int i = 0; i < 4; ++i) {
#pragma unroll
                    for (int kk = 0; kk < 4; ++kk) {
                        float x1 = (kk == 0) ? a1[i].x : (kk == 1) ? a1[i].y : (kk == 2) ? a1[i].z : a1[i].w;
                        float x2 = (kk == 0) ? a2[i].x : (kk == 1) ? a2[i].y : (kk == 2) ? a2[i].z : a2[i].w;
#pragma unroll
                        for (int j = 0; j < 8; ++j)
                            acc[h * 4 + i][j] = fmaf(x1, w1v[kk][j], fmaf(x2, w2v[kk][j], acc[h * 4 + i][j]));
                    }
                }
            }
        }
    }
    float bv[8];
    *(float4*)&bv[0] = *(const float4*)(b1 + c0a);
    *(float4*)&bv[4] = *(const float4*)(b1 + c0b);
#pragma unroll
    for (int i = 0; i < 8; ++i) {
        int n = n0 + i;
        if (n < NN) {
            float* orow = out + (size_t)n * 128;
            float4 v;
            v.x = gelu_f(acc[i][0] + bv[0]);
            v.y = gelu_f(acc[i][1] + bv[1]);
            v.z = gelu_f(acc[i][2] + bv[2]);
            v.w = gelu_f(acc[i][3] + bv[3]);
            *(float4*)(orow + c0a) = v;
            v.x = gelu_f(acc[i][4] + bv[4]);
            v.y = gelu_f(acc[i][5] + bv[5]);
            v.z = gelu_f(acc[i][6] + bv[6]);
            v.w = gelu_f(acc[i][7] + bv[7]);
            *(float4*)(orow + c0b) = v;
        }
    }
}

// ---------------- fused gate: gate[n] = gelu(H@Wg1+bg1) . Wg2   (bg2 dropped:
// per-graph softmax is invariant to a constant shift of the scores) ----------------
__global__ __launch_bounds__(512, 2) void k_gatef(const float* __restrict__ H, const float* __restrict__ Wg1,
                                                  const float* __restrict__ bg1, const float* __restrict__ Wg2,
                                                  float* __restrict__ gate) {
    __shared__ float wgs[16384];  // full Wg1 [128][128]
    const int t = threadIdx.x;
    for (int idx = t; idx < 4096; idx += 512)
        ((float4*)wgs)[idx] = ((const float4*)Wg1)[idx];
    __syncthreads();
    const int cg = t & 15;
    const int ng = t >> 4;
    const int n0 = blockIdx.x * 256 + ng * 8;
    const int c0a = cg * 4;
    const int c0b = 64 + cg * 4;
    float acc[8][8];
#pragma unroll
    for (int i = 0; i < 8; ++i)
#pragma unroll
        for (int j = 0; j < 8; ++j) acc[i][j] = 0.f;
    const float* r1[8];
#pragma unroll
    for (int i = 0; i < 8; ++i) {
        int n = n0 + i;
        if (n >= NN) n = NN - 1;
        r1[i] = H + (size_t)n * 128;
    }
    for (int k = 0; k < 128; k += 4) {
        float w1v[4][8];
#pragma unroll
        for (int kk = 0; kk < 4; ++kk) {
            *(float4*)&w1v[kk][0] = *(const float4*)&wgs[(k + kk) * 128 + c0a];
            *(float4*)&w1v[kk][4] = *(const float4*)&wgs[(k + kk) * 128 + c0b];
        }
#pragma unroll
        for (int h = 0; h < 2; ++h) {
            float4 a1[4];
#pragma unroll
            for (int i = 0; i < 4; ++i) a1[i] = *(const float4*)(r1[h * 4 + i] + k);
#pragma unroll
            for (int i = 0; i < 4; ++i) {
#pragma unroll
                for (int kk = 0; kk < 4; ++kk) {
                    float x1 = (kk == 0) ? a1[i].x : (kk == 1) ? a1[i].y : (kk == 2) ? a1[i].z : a1[i].w;
#pragma unroll
                    for (int j = 0; j < 8; ++j)
                        acc[h * 4 + i][j] = fmaf(x1, w1v[kk][j], acc[h * 4 + i][j]);
                }
            }
        }
    }
    float bv[8], gv[8];
    *(float4*)&bv[0] = *(const float4*)(bg1 + c0a);
    *(float4*)&bv[4] = *(const float4*)(bg1 + c0b);
    *(float4*)&gv[0] = *(const float4*)(Wg2 + c0a);
    *(float4*)&gv[4] = *(const float4*)(Wg2 + c0b);
    float part[8];
#pragma unroll
    for (int i = 0; i < 8; ++i) {
        float p = 0.f;
#pragma unroll
        for (int j = 0; j < 8; ++j) p += gelu_f(acc[i][j] + bv[j]) * gv[j];
        part[i] = p;
    }
#pragma unroll
    for (int m = 1; m < 16; m <<= 1) {
#pragma unroll
        for (int i = 0; i < 8; ++i) part[i] += __shfl_xor(part[i], m);
    }
    if (cg == 0) {
#pragma unroll
        for (int i = 0; i < 8; ++i) {
            int n = n0 + i;
            if (n < NN) gate[n] = part[i];
        }
    }
}

// ---------------- pooling stage 1: per-graph max + exp-sum over gate ----------------
__global__ __launch_bounds__(256) void k_pstats(const float* __restrict__ gate, const int* __restrict__ batch,
                                                float* __restrict__ gm, float* __restrict__ gden) {
    int g = blockIdx.x;
    int lo = 0, hi = NN;
    while (lo < hi) { int mid = (lo + hi) >> 1; if (batch[mid] < g) lo = mid + 1; else hi = mid; }
    int start = lo;
    lo = start; hi = NN;
    while (lo < hi) { int mid = (lo + hi) >> 1; if (batch[mid] < g + 1) lo = mid + 1; else hi = mid; }
    int endp = lo;

    __shared__ float red[256];
    int tid = threadIdx.x;

    float m = -1e30f;
    for (int i = start + tid; i < endp; i += 256) m = fmaxf(m, gate[i]);
    red[tid] = m;
    __syncthreads();
    for (int off = 128; off; off >>= 1) {
        if (tid < off) red[tid] = fmaxf(red[tid], red[tid + off]);
        __syncthreads();
    }
    m = red[0];
    __syncthreads();

    float s = 0.f;
    for (int i = start + tid; i < endp; i += 256) s += expf(gate[i] - m);
    red[tid] = s;
    __syncthreads();
    for (int off = 128; off; off >>= 1) {
        if (tid < off) red[tid] += red[tid + off];
        __syncthreads();
    }
    if (tid == 0) { gm[g] = m; gden[g] = red[0]; }
}

// ---------------- pooling stage 2: node-parallel weighted accumulate ----------------
// 128-node tile per block; 2 threads per column. Sorted batch -> register-run
// accumulation, one atomicAdd per (graph-run, thread).
__global__ __launch_bounds__(256) void k_pacc(const float* __restrict__ H, const float* __restrict__ gate,
                                              const int* __restrict__ batch, const float* __restrict__ gm,
                                              const float* __restrict__ gden, float* __restrict__ gacc) {
    int c = threadIdx.x & 127;
    int h = threadIdx.x >> 7;
    int n0 = blockIdx.x * 128;
    int nend = n0 + 128;
    if (nend > NN) nend = NN;
    int i = n0 + h;
    if (i >= nend) return;
    int cur = batch[i];
    float m = gm[cur], invd = 1.0f / gden[cur];
    float acc = 0.f;
    for (; i < nend; i += 2) {
        int gi = batch[i];
        if (gi != cur) {
            atomicAdd(&gacc[cur * 128 + c], acc * invd);
            acc = 0.f;
            cur = gi;
            m = gm[cur];
            invd = 1.0f / gden[cur];
        }
        acc = fmaf(expf(gate[i] - m), H[(size_t)i * 128 + c], acc);
    }
    atomicAdd(&gacc[cur * 128 + c], acc * invd);
}

// ---------------- head: out[g] = g . Wh + bh ----------------
__global__ __launch_bounds__(64) void k_head(const float* __restrict__ gacc, const float* __restrict__ Wh,
                                             const float* __restrict__ bh, float* __restrict__ out) {
    int g = blockIdx.x;
    int l = threadIdx.x;
    float v = gacc[g * 128 + l] * Wh[l] + gacc[g * 128 + 64 + l] * Wh[64 + l];
#pragma unroll
    for (int m = 1; m < 64; m <<= 1) v += __shfl_xor(v, m);
    if (l == 0) out[g] = v + bh[0];
}

extern "C" void kernel_launch(void* const* d_in, const int* in_sizes, int n_in,
                              void* d_out, int out_size, void* d_ws, size_t ws_size,
                              hipStream_t stream) {
    (void)in_sizes; (void)n_in; (void)out_size; (void)ws_size;
    const float* x   = (const float*)d_in[0];
    const int*  ei   = (const int*)d_in[1];
    const int*  batch= (const int*)d_in[2];
    const float* Wl0 = (const float*)d_in[3];
    const float* bl0 = (const float*)d_in[4];
    const float* Wr0 = (const float*)d_in[5];
    const float* Wl1 = (const float*)d_in[6];
    const float* bl1 = (const float*)d_in[7];
    const float* Wr1 = (const float*)d_in[8];
    const float* Wg1 = (const float*)d_in[9];
    const float* bg1 = (const float*)d_in[10];
    const float* Wg2 = (const float*)d_in[11];
    const float* Wh  = (const float*)d_in[13];
    const float* bh  = (const float*)d_in[14];
    float* out = (float*)d_out;

    const int* srcp = ei;
    const int* dstp = ei + NE;

    char* w = (char*)d_ws;
    size_t off = 0;
    auto alloc = [&](size_t bytes) { void* p = w + off; off += (bytes + 255) & ~(size_t)255; return p; };
    float* bufA  = (float*)alloc((size_t)NN * 128 * 4);  // agg / h2
    float* bufH  = (float*)alloc((size_t)NN * 128 * 4);  // h1
    float* gate  = (float*)alloc((size_t)NN * 4);
    int* cnt     = (int*)alloc((size_t)NN * 4);
    int* rowp    = (int*)alloc((size_t)(NN + 1) * 4);
    int* fill    = (int*)alloc((size_t)NN * 4);
    int* cidx    = (int*)alloc((size_t)NE * 4);
    int* blksum  = (int*)alloc(128 * 4);
    int* blkoff  = (int*)alloc(128 * 4);
    float* gm    = (float*)alloc(NG * 4);
    float* gden  = (float*)alloc(NG * 4);
    float* gacc  = (float*)alloc((size_t)NG * 128 * 4);

    hipMemsetAsync(cnt, 0, (size_t)NN * 4, stream);
    hipMemsetAsync(fill, 0, (size_t)NN * 4, stream);
    hipMemsetAsync(gacc, 0, (size_t)NG * 128 * 4, stream);

    // CSR build (reused by both layers)
    k_hist<<<(NE + 255) / 256, 256, 0, stream>>>(dstp, cnt);
    int nb = (NN + SB - 1) / SB;
    k_scan1<<<nb, SB, 0, stream>>>(cnt, rowp, blksum);
    k_scan2<<<1, 128, 0, stream>>>(blksum, blkoff, nb);
    k_scan3<<<(NN + 1 + 255) / 256, 256, 0, stream>>>(rowp, blkoff);
    k_scatter<<<(NE + 255) / 256, 256, 0, stream>>>(srcp, dstp, rowp, fill, cidx);

    int gs = (NN + 255) / 256;           // 512-thread GEMM blocks (256-node tiles)
    int ga = (NN * 32 + 255) / 256;      // k_agg: 32 lanes per node
    // layer 0
    k_agg<<<ga, 256, 0, stream>>>(x, rowp, cidx, bufA);
    k_sage<<<gs, 512, 0, stream>>>(bufA, Wl0, bl0, x, Wr0, bufH);      // h1
    // layer 1
    k_agg<<<ga, 256, 0, stream>>>(bufH, rowp, cidx, bufA);
    k_sage<<<gs, 512, 0, stream>>>(bufA, Wl1, bl1, bufH, Wr1, bufA);   // h2 in-place (wave-owned rows)
    // gate + pool + head
    k_gatef<<<gs, 512, 0, stream>>>(bufA, Wg1, bg1, Wg2, gate);
    k_pstats<<<NG, 256, 0, stream>>>(gate, batch, gm, gden);
    k_pacc<<<(NN + 127) / 128, 256, 0, stream>>>(bufA, gate, batch, gm, gden, gacc);
    k_head<<<NG, 64, 0, stream>>>(gacc, Wh, bh, out);
}

// Round 6
// 766.794 us; speedup vs baseline: 2.1728x; 1.0043x over previous
//
#include <hip/hip_runtime.h>
#include <math.h>

#define NN 100000
#define NE 1600000
#define NG 64

__device__ __forceinline__ float gelu_f(float x) {
    return 0.5f * x * (1.0f + erff(x * 0.7071067811865475f));
}

// ---------------- CSR build ----------------
__global__ void k_hist(const int* __restrict__ dstp, int* __restrict__ cnt) {
    int e = blockIdx.x * 256 + threadIdx.x;
    if (e < NE) atomicAdd(&cnt[dstp[e]], 1);
}

#define SB 1024
__global__ __launch_bounds__(SB) void k_scan1(const int* __restrict__ cnt, int* __restrict__ rowp,
                                              int* __restrict__ blksum) {
    __shared__ int s[SB];
    int tid = threadIdx.x;
    int i = blockIdx.x * SB + tid;
    int v = (i < NN) ? cnt[i] : 0;
    int run = v;
    s[tid] = v;
    __syncthreads();
    for (int off = 1; off < SB; off <<= 1) {
        int t = (tid >= off) ? s[tid - off] : 0;
        __syncthreads();
        run += t;
        s[tid] = run;
        __syncthreads();
    }
    if (i < NN) rowp[i] = run - v;            // exclusive within block
    if (tid == SB - 1) blksum[blockIdx.x] = run;
}

__global__ void k_scan2(const int* __restrict__ blksum, int* __restrict__ blkoff, int nb) {
    __shared__ int s[128];
    int tid = threadIdx.x;
    int v = (tid < nb) ? blksum[tid] : 0;
    int run = v;
    s[tid] = v;
    __syncthreads();
    for (int off = 1; off < 128; off <<= 1) {
        int t = (tid >= off) ? s[tid - off] : 0;
        __syncthreads();
        run += t;
        s[tid] = run;
        __syncthreads();
    }
    if (tid < nb) blkoff[tid] = run - v;
}

__global__ void k_scan3(int* __restrict__ rowp, const int* __restrict__ blkoff) {
    int i = blockIdx.x * 256 + threadIdx.x;
    if (i < NN) rowp[i] += blkoff[i >> 10];
    else if (i == NN) rowp[NN] = NE;
}

__global__ void k_scatter(const int* __restrict__ srcp, const int* __restrict__ dstp,
                          const int* __restrict__ rowp, int* __restrict__ fill,
                          int* __restrict__ cidx) {
    int e = blockIdx.x * 256 + threadIdx.x;
    if (e < NE) {
        int d = dstp[e];
        int pos = atomicAdd(&fill[d], 1);
        cidx[rowp[d] + pos] = srcp[e];
    }
}

// ---------------- mean-aggregate: 32 lanes x float4 per node, 8 edges in flight ----------------
__global__ __launch_bounds__(256) void k_agg(const float* __restrict__ xin, const int* __restrict__ rowp,
                                             const int* __restrict__ cidx, float* __restrict__ agg) {
    int tid = blockIdx.x * 256 + threadIdx.x;
    int node = tid >> 5;
    int lane = tid & 31;
    if (node >= NN) return;
    int beg = rowp[node], endp = rowp[node + 1];
    const float4* x4 = (const float4*)xin;
    float sx = 0.f, sy = 0.f, sz = 0.f, sw = 0.f;
    int e = beg;
    for (; e + 7 < endp; e += 8) {
        int i0 = cidx[e],     i1 = cidx[e + 1], i2 = cidx[e + 2], i3 = cidx[e + 3];
        int i4 = cidx[e + 4], i5 = cidx[e + 5], i6 = cidx[e + 6], i7 = cidx[e + 7];
        float4 v0 = x4[(size_t)i0 * 32 + lane];
        float4 v1 = x4[(size_t)i1 * 32 + lane];
        float4 v2 = x4[(size_t)i2 * 32 + lane];
        float4 v3 = x4[(size_t)i3 * 32 + lane];
        float4 v4 = x4[(size_t)i4 * 32 + lane];
        float4 v5 = x4[(size_t)i5 * 32 + lane];
        float4 v6 = x4[(size_t)i6 * 32 + lane];
        float4 v7 = x4[(size_t)i7 * 32 + lane];
        sx += ((v0.x + v1.x) + (v2.x + v3.x)) + ((v4.x + v5.x) + (v6.x + v7.x));
        sy += ((v0.y + v1.y) + (v2.y + v3.y)) + ((v4.y + v5.y) + (v6.y + v7.y));
        sz += ((v0.z + v1.z) + (v2.z + v3.z)) + ((v4.z + v5.z) + (v6.z + v7.z));
        sw += ((v0.w + v1.w) + (v2.w + v3.w)) + ((v4.w + v5.w) + (v6.w + v7.w));
    }
    for (; e + 3 < endp; e += 4) {
        int i0 = cidx[e], i1 = cidx[e + 1], i2 = cidx[e + 2], i3 = cidx[e + 3];
        float4 v0 = x4[(size_t)i0 * 32 + lane];
        float4 v1 = x4[(size_t)i1 * 32 + lane];
        float4 v2 = x4[(size_t)i2 * 32 + lane];
        float4 v3 = x4[(size_t)i3 * 32 + lane];
        sx += (v0.x + v1.x) + (v2.x + v3.x);
        sy += (v0.y + v1.y) + (v2.y + v3.y);
        sz += (v0.z + v1.z) + (v2.z + v3.z);
        sw += (v0.w + v1.w) + (v2.w + v3.w);
    }
    for (; e < endp; ++e) {
        int i0 = cidx[e];
        float4 v0 = x4[(size_t)i0 * 32 + lane];
        sx += v0.x; sy += v0.y; sz += v0.z; sw += v0.w;
    }
    float inv = 1.0f / fmaxf((float)(endp - beg), 1.0f);
    float4 r;
    r.x = sx * inv; r.y = sy * inv; r.z = sz * inv; r.w = sw * inv;
    ((float4*)agg)[(size_t)node * 32 + lane] = r;
}

// ---------------- fused SAGE layer: out = gelu(A1@W1 + b1 + A2@W2) ----------------
// 256 threads; tile = 128 nodes x 128 cols; thread = 8 nodes x 8 cols.
// W1,W2 staged in 32KB LDS as 32-row k-quarters -> 4-5 blocks/CU (16 waves, VGPR class 116).
// NOTE: plain __launch_bounds__(256): round-4's (256,4) min-waves arg capped VGPRs
// at 64 -> accumulator spills -> 1.17GB scratch traffic. Do not re-add it.
// Thread cols split {cg*4..+3} u {64+cg*4..+3}: ds_read_b128 spans contiguous
// 256B across the 16 cg-lanes (2 lanes/bank = conflict-free).
// In-place safety (out may alias A1): each node row is read/written ONLY by the 16
// consecutive threads (same wave) owning it; wave lockstep orders k-loop loads
// before epilogue stores. Clamped tail reads are discarded.
__global__ __launch_bounds__(256) void k_sage(const float* A1, const float* __restrict__ W1,
                                              const float* __restrict__ b1, const float* A2,
                                              const float* __restrict__ W2, float* out) {
    __shared__ float ws[8192];  // [0..4095]: W1 quarter [32][128]; [4096..]: W2 quarter
    const int t = threadIdx.x;
    const int cg = t & 15;
    const int ng = t >> 4;
    const int n0 = blockIdx.x * 128 + ng * 8;
    const int c0a = cg * 4;
    const int c0b = 64 + cg * 4;
    float acc[8][8];
#pragma unroll
    for (int i = 0; i < 8; ++i)
#pragma unroll
        for (int j = 0; j < 8; ++j) acc[i][j] = 0.f;
    const float *r1[8], *r2[8];
#pragma unroll
    for (int i = 0; i < 8; ++i) {
        int n = n0 + i;
        if (n >= NN) n = NN - 1;  // clamp loads; stores guarded below
        r1[i] = A1 + (size_t)n * 128;
        r2[i] = A2 + (size_t)n * 128;
    }
    for (int kb = 0; kb < 128; kb += 32) {
        __syncthreads();  // previous quarter fully consumed before overwrite
        {
            const float4* w1q = (const float4*)(W1 + kb * 128);
            const float4* w2q = (const float4*)(W2 + kb * 128);
#pragma unroll
            for (int u = 0; u < 4; ++u) {
                int idx = t + u * 256;  // 1024 float4 per matrix quarter
                ((float4*)ws)[idx] = w1q[idx];
                ((float4*)(ws + 4096))[idx] = w2q[idx];
            }
        }
        __syncthreads();
        for (int k2 = 0; k2 < 32; k2 += 4) {
            const int k = kb + k2;
            float w1v[4][8], w2v[4][8];
#pragma unroll
            for (int kk = 0; kk < 4; ++kk) {
                *(float4*)&w1v[kk][0] = *(const float4*)&ws[(k2 + kk) * 128 + c0a];
                *(float4*)&w1v[kk][4] = *(const float4*)&ws[(k2 + kk) * 128 + c0b];
                *(float4*)&w2v[kk][0] = *(const float4*)&ws[4096 + (k2 + kk) * 128 + c0a];
                *(float4*)&w2v[kk][4] = *(const float4*)&ws[4096 + (k2 + kk) * 128 + c0b];
            }
#pragma unroll
            for (int h = 0; h < 2; ++h) {
                float4 a1[4], a2[4];
#pragma unroll
                for (int i = 0; i < 4; ++i) {
                    a1[i] = *(const float4*)(r1[h * 4 + i] + k);
                    a2[i] = *(const float4*)(r2[h * 4 + i] + k);
                }
#pragma unroll
                for (int i = 0; i < 4; ++i) {
#pragma unroll
                    for (int kk = 0; kk < 4; ++kk) {
                        float x1 = (kk == 0) ? a1[i].x : (kk == 1) ? a1[i].y : (kk == 2) ? a1[i].z : a1[i].w;
                        float x2 = (kk == 0) ? a2[i].x : (kk == 1) ? a2[i].y : (kk == 2) ? a2[i].z : a2[i].w;
#pragma unroll
                        for (int j = 0; j < 8; ++j)
                            acc[h * 4 + i][j] = fmaf(x1, w1v[kk][j], fmaf(x2, w2v[kk][j], acc[h * 4 + i][j]));
                    }
                }
            }
        }
    }
    float bv[8];
    *(float4*)&bv[0] = *(const float4*)(b1 + c0a);
    *(float4*)&bv[4] = *(const float4*)(b1 + c0b);
#pragma unroll
    for (int i = 0; i < 8; ++i) {
        int n = n0 + i;
        if (n < NN) {
            float* orow = out + (size_t)n * 128;
            float4 v;
            v.x = gelu_f(acc[i][0] + bv[0]);
            v.y = gelu_f(acc[i][1] + bv[1]);
            v.z = gelu_f(acc[i][2] + bv[2]);
            v.w = gelu_f(acc[i][3] + bv[3]);
            *(float4*)(orow + c0a) = v;
            v.x = gelu_f(acc[i][4] + bv[4]);
            v.y = gelu_f(acc[i][5] + bv[5]);
            v.z = gelu_f(acc[i][6] + bv[6]);
            v.w = gelu_f(acc[i][7] + bv[7]);
            *(float4*)(orow + c0b) = v;
        }
    }
}

// ---------------- fused gate: gate[n] = gelu(H@Wg1+bg1) . Wg2   (bg2 dropped:
// per-graph softmax is invariant to a constant shift of the scores) ----------------
__global__ __launch_bounds__(256) void k_gatef(const float* __restrict__ H, const float* __restrict__ Wg1,
                                               const float* __restrict__ bg1, const float* __restrict__ Wg2,
                                               float* __restrict__ gate) {
    __shared__ float ws[4096];  // Wg1 quarter [32][128] = 16KB
    const int t = threadIdx.x;
    const int cg = t & 15;
    const int ng = t >> 4;
    const int n0 = blockIdx.x * 128 + ng * 8;
    const int c0a = cg * 4;
    const int c0b = 64 + cg * 4;
    float acc[8][8];
#pragma unroll
    for (int i = 0; i < 8; ++i)
#pragma unroll
        for (int j = 0; j < 8; ++j) acc[i][j] = 0.f;
    const float* r1[8];
#pragma unroll
    for (int i = 0; i < 8; ++i) {
        int n = n0 + i;
        if (n >= NN) n = NN - 1;
        r1[i] = H + (size_t)n * 128;
    }
    for (int kb = 0; kb < 128; kb += 32) {
        __syncthreads();
        {
            const float4* wq = (const float4*)(Wg1 + kb * 128);
#pragma unroll
            for (int u = 0; u < 4; ++u) {
                int idx = t + u * 256;
                ((float4*)ws)[idx] = wq[idx];
            }
        }
        __syncthreads();
        for (int k2 = 0; k2 < 32; k2 += 4) {
            const int k = kb + k2;
            float w1v[4][8];
#pragma unroll
            for (int kk = 0; kk < 4; ++kk) {
                *(float4*)&w1v[kk][0] = *(const float4*)&ws[(k2 + kk) * 128 + c0a];
                *(float4*)&w1v[kk][4] = *(const float4*)&ws[(k2 + kk) * 128 + c0b];
            }
#pragma unroll
            for (int h = 0; h < 2; ++h) {
                float4 a1[4];
#pragma unroll
                for (int i = 0; i < 4; ++i) a1[i] = *(const float4*)(r1[h * 4 + i] + k);
#pragma unroll
                for (int i = 0; i < 4; ++i) {
#pragma unroll
                    for (int kk = 0; kk < 4; ++kk) {
                        float x1 = (kk == 0) ? a1[i].x : (kk == 1) ? a1[i].y : (kk == 2) ? a1[i].z : a1[i].w;
#pragma unroll
                        for (int j = 0; j < 8; ++j)
                            acc[h * 4 + i][j] = fmaf(x1, w1v[kk][j], acc[h * 4 + i][j]);
                    }
                }
            }
        }
    }
    float bv[8], gv[8];
    *(float4*)&bv[0] = *(const float4*)(bg1 + c0a);
    *(float4*)&bv[4] = *(const float4*)(bg1 + c0b);
    *(float4*)&gv[0] = *(const float4*)(Wg2 + c0a);
    *(float4*)&gv[4] = *(const float4*)(Wg2 + c0b);
    float part[8];
#pragma unroll
    for (int i = 0; i < 8; ++i) {
        float p = 0.f;
#pragma unroll
        for (int j = 0; j < 8; ++j) p += gelu_f(acc[i][j] + bv[j]) * gv[j];
        part[i] = p;
    }
#pragma unroll
    for (int m = 1; m < 16; m <<= 1) {
#pragma unroll
        for (int i = 0; i < 8; ++i) part[i] += __shfl_xor(part[i], m);
    }
    if (cg == 0) {
#pragma unroll
        for (int i = 0; i < 8; ++i) {
            int n = n0 + i;
            if (n < NN) gate[n] = part[i];
        }
    }
}

// ---------------- pooling stage 1: per-graph max + exp-sum over gate ----------------
__global__ __launch_bounds__(256) void k_pstats(const float* __restrict__ gate, const int* __restrict__ batch,
                                                float* __restrict__ gm, float* __restrict__ gden) {
    int g = blockIdx.x;
    int lo = 0, hi = NN;
    while (lo < hi) { int mid = (lo + hi) >> 1; if (batch[mid] < g) lo = mid + 1; else hi = mid; }
    int start = lo;
    lo = start; hi = NN;
    while (lo < hi) { int mid = (lo + hi) >> 1; if (batch[mid] < g + 1) lo = mid + 1; else hi = mid; }
    int endp = lo;

    __shared__ float red[256];
    int tid = threadIdx.x;

    float m = -1e30f;
    for (int i = start + tid; i < endp; i += 256) m = fmaxf(m, gate[i]);
    red[tid] = m;
    __syncthreads();
    for (int off = 128; off; off >>= 1) {
        if (tid < off) red[tid] = fmaxf(red[tid], red[tid + off]);
        __syncthreads();
    }
    m = red[0];
    __syncthreads();

    float s = 0.f;
    for (int i = start + tid; i < endp; i += 256) s += expf(gate[i] - m);
    red[tid] = s;
    __syncthreads();
    for (int off = 128; off; off >>= 1) {
        if (tid < off) red[tid] += red[tid + off];
        __syncthreads();
    }
    if (tid == 0) { gm[g] = m; gden[g] = red[0]; }
}

// ---------------- pooling stage 2: node-parallel weighted accumulate ----------------
// 128-node tile per block; 2 threads per column. Sorted batch -> register-run
// accumulation, one atomicAdd per (graph-run, thread).
__global__ __launch_bounds__(256) void k_pacc(const float* __restrict__ H, const float* __restrict__ gate,
                                              const int* __restrict__ batch, const float* __restrict__ gm,
                                              const float* __restrict__ gden, float* __restrict__ gacc) {
    int c = threadIdx.x & 127;
    int h = threadIdx.x >> 7;
    int n0 = blockIdx.x * 128;
    int nend = n0 + 128;
    if (nend > NN) nend = NN;
    int i = n0 + h;
    if (i >= nend) return;
    int cur = batch[i];
    float m = gm[cur], invd = 1.0f / gden[cur];
    float acc = 0.f;
    for (; i < nend; i += 2) {
        int gi = batch[i];
        if (gi != cur) {
            atomicAdd(&gacc[cur * 128 + c], acc * invd);
            acc = 0.f;
            cur = gi;
            m = gm[cur];
            invd = 1.0f / gden[cur];
        }
        acc = fmaf(expf(gate[i] - m), H[(size_t)i * 128 + c], acc);
    }
    atomicAdd(&gacc[cur * 128 + c], acc * invd);
}

// ---------------- head: out[g] = g . Wh + bh ----------------
__global__ __launch_bounds__(64) void k_head(const float* __restrict__ gacc, const float* __restrict__ Wh,
                                             const float* __restrict__ bh, float* __restrict__ out) {
    int g = blockIdx.x;
    int l = threadIdx.x;
    float v = gacc[g * 128 + l] * Wh[l] + gacc[g * 128 + 64 + l] * Wh[64 + l];
#pragma unroll
    for (int m = 1; m < 64; m <<= 1) v += __shfl_xor(v, m);
    if (l == 0) out[g] = v + bh[0];
}

extern "C" void kernel_launch(void* const* d_in, const int* in_sizes, int n_in,
                              void* d_out, int out_size, void* d_ws, size_t ws_size,
                              hipStream_t stream) {
    (void)in_sizes; (void)n_in; (void)out_size; (void)ws_size;
    const float* x   = (const float*)d_in[0];
    const int*  ei   = (const int*)d_in[1];
    const int*  batch= (const int*)d_in[2];
    const float* Wl0 = (const float*)d_in[3];
    const float* bl0 = (const float*)d_in[4];
    const float* Wr0 = (const float*)d_in[5];
    const float* Wl1 = (const float*)d_in[6];
    const float* bl1 = (const float*)d_in[7];
    const float* Wr1 = (const float*)d_in[8];
    const float* Wg1 = (const float*)d_in[9];
    const float* bg1 = (const float*)d_in[10];
    const float* Wg2 = (const float*)d_in[11];
    const float* Wh  = (const float*)d_in[13];
    const float* bh  = (const float*)d_in[14];
    float* out = (float*)d_out;

    const int* srcp = ei;
    const int* dstp = ei + NE;

    char* w = (char*)d_ws;
    size_t off = 0;
    auto alloc = [&](size_t bytes) { void* p = w + off; off += (bytes + 255) & ~(size_t)255; return p; };
    float* bufA  = (float*)alloc((size_t)NN * 128 * 4);  // agg / h2
    float* bufH  = (float*)alloc((size_t)NN * 128 * 4);  // h1
    float* gate  = (float*)alloc((size_t)NN * 4);
    int* cnt     = (int*)alloc((size_t)NN * 4);
    int* rowp    = (int*)alloc((size_t)(NN + 1) * 4);
    int* fill    = (int*)alloc((size_t)NN * 4);
    int* cidx    = (int*)alloc((size_t)NE * 4);
    int* blksum  = (int*)alloc(128 * 4);
    int* blkoff  = (int*)alloc(128 * 4);
    float* gm    = (float*)alloc(NG * 4);
    float* gden  = (float*)alloc(NG * 4);
    float* gacc  = (float*)alloc((size_t)NG * 128 * 4);

    hipMemsetAsync(cnt, 0, (size_t)NN * 4, stream);
    hipMemsetAsync(fill, 0, (size_t)NN * 4, stream);
    hipMemsetAsync(gacc, 0, (size_t)NG * 128 * 4, stream);

    // CSR build (reused by both layers)
    k_hist<<<(NE + 255) / 256, 256, 0, stream>>>(dstp, cnt);
    int nb = (NN + SB - 1) / SB;
    k_scan1<<<nb, SB, 0, stream>>>(cnt, rowp, blksum);
    k_scan2<<<1, 128, 0, stream>>>(blksum, blkoff, nb);
    k_scan3<<<(NN + 1 + 255) / 256, 256, 0, stream>>>(rowp, blkoff);
    k_scatter<<<(NE + 255) / 256, 256, 0, stream>>>(srcp, dstp, rowp, fill, cidx);

    int gs = (NN + 127) / 128;           // 256-thread GEMM blocks (128-node tiles) -> 782 blocks
    int ga = (NN * 32 + 255) / 256;      // k_agg: 32 lanes per node
    // layer 0
    k_agg<<<ga, 256, 0, stream>>>(x, rowp, cidx, bufA);
    k_sage<<<gs, 256, 0, stream>>>(bufA, Wl0, bl0, x, Wr0, bufH);      // h1
    // layer 1
    k_agg<<<ga, 256, 0, stream>>>(bufH, rowp, cidx, bufA);
    k_sage<<<gs, 256, 0, stream>>>(bufA, Wl1, bl1, bufH, Wr1, bufA);   // h2 in-place (wave-owned rows)
    // gate + pool + head
    k_gatef<<<gs, 256, 0, stream>>>(bufA, Wg1, bg1, Wg2, gate);
    k_pstats<<<NG, 256, 0, stream>>>(gate, batch, gm, gden);
    k_pacc<<<(NN + 127) / 128, 256, 0, stream>>>(bufA, gate, batch, gm, gden, gacc);
    k_head<<<NG, 64, 0, stream>>>(gacc, Wh, bh, out);
}

// Round 7
// 664.312 us; speedup vs baseline: 2.5080x; 1.1543x over previous
//
#include <hip/hip_runtime.h>
#include <math.h>

#define NN 100000
#define NE 1600000
#define NG 64

typedef unsigned short u16;
typedef unsigned int u32;
typedef __attribute__((ext_vector_type(8))) short short8;   // 8 bf16 = 4 VGPR
typedef __attribute__((ext_vector_type(4))) float f32x4;    // MFMA C/D

__device__ __forceinline__ float gelu_f(float x) {
    return 0.5f * x * (1.0f + erff(x * 0.7071067811865475f));
}
// round-to-nearest-even fp32 -> bf16 (no NaN inputs expected)
__device__ __forceinline__ u16 f2bf(float f) {
    u32 u = __float_as_uint(f);
    u32 r = u + 0x7FFFu + ((u >> 16) & 1u);
    return (u16)(r >> 16);
}
__device__ __forceinline__ float bf2f(u16 h) {
    return __uint_as_float(((u32)h) << 16);
}
// load 8 consecutive fp32, produce hi/lo bf16x8 split (a ~= hi + lo, rel err ~2^-18)
__device__ __forceinline__ void cvt8(const float* p, short8& hi, short8& lo) {
    float4 f0 = *(const float4*)p;
    float4 f1 = *(const float4*)(p + 4);
    float v[8] = {f0.x, f0.y, f0.z, f0.w, f1.x, f1.y, f1.z, f1.w};
#pragma unroll
    for (int e = 0; e < 8; ++e) {
        u16 h = f2bf(v[e]);
        hi[e] = (short)h;
        lo[e] = (short)f2bf(v[e] - bf2f(h));
    }
}
#define MFMA __builtin_amdgcn_mfma_f32_16x16x32_bf16

// ---------------- CSR build ----------------
__global__ void k_hist(const int* __restrict__ dstp, int* __restrict__ cnt) {
    int e = blockIdx.x * 256 + threadIdx.x;
    if (e < NE) atomicAdd(&cnt[dstp[e]], 1);
}

#define SB 1024
__global__ __launch_bounds__(SB) void k_scan1(const int* __restrict__ cnt, int* __restrict__ rowp,
                                              int* __restrict__ blksum) {
    __shared__ int s[SB];
    int tid = threadIdx.x;
    int i = blockIdx.x * SB + tid;
    int v = (i < NN) ? cnt[i] : 0;
    int run = v;
    s[tid] = v;
    __syncthreads();
    for (int off = 1; off < SB; off <<= 1) {
        int t = (tid >= off) ? s[tid - off] : 0;
        __syncthreads();
        run += t;
        s[tid] = run;
        __syncthreads();
    }
    if (i < NN) rowp[i] = run - v;            // exclusive within block
    if (tid == SB - 1) blksum[blockIdx.x] = run;
}

__global__ void k_scan2(const int* __restrict__ blksum, int* __restrict__ blkoff, int nb) {
    __shared__ int s[128];
    int tid = threadIdx.x;
    int v = (tid < nb) ? blksum[tid] : 0;
    int run = v;
    s[tid] = v;
    __syncthreads();
    for (int off = 1; off < 128; off <<= 1) {
        int t = (tid >= off) ? s[tid - off] : 0;
        __syncthreads();
        run += t;
        s[tid] = run;
        __syncthreads();
    }
    if (tid < nb) blkoff[tid] = run - v;
}

__global__ void k_scan3(int* __restrict__ rowp, const int* __restrict__ blkoff) {
    int i = blockIdx.x * 256 + threadIdx.x;
    if (i < NN) rowp[i] += blkoff[i >> 10];
    else if (i == NN) rowp[NN] = NE;
}

__global__ void k_scatter(const int* __restrict__ srcp, const int* __restrict__ dstp,
                          const int* __restrict__ rowp, int* __restrict__ fill,
                          int* __restrict__ cidx) {
    int e = blockIdx.x * 256 + threadIdx.x;
    if (e < NE) {
        int d = dstp[e];
        int pos = atomicAdd(&fill[d], 1);
        cidx[rowp[d] + pos] = srcp[e];
    }
}

// ---------------- mean-aggregate: 32 lanes x float4 per node, 8 edges in flight ----------------
__global__ __launch_bounds__(256) void k_agg(const float* __restrict__ xin, const int* __restrict__ rowp,
                                             const int* __restrict__ cidx, float* __restrict__ agg) {
    int tid = blockIdx.x * 256 + threadIdx.x;
    int node = tid >> 5;
    int lane = tid & 31;
    if (node >= NN) return;
    int beg = rowp[node], endp = rowp[node + 1];
    const float4* x4 = (const float4*)xin;
    float sx = 0.f, sy = 0.f, sz = 0.f, sw = 0.f;
    int e = beg;
    for (; e + 7 < endp; e += 8) {
        int i0 = cidx[e],     i1 = cidx[e + 1], i2 = cidx[e + 2], i3 = cidx[e + 3];
        int i4 = cidx[e + 4], i5 = cidx[e + 5], i6 = cidx[e + 6], i7 = cidx[e + 7];
        float4 v0 = x4[(size_t)i0 * 32 + lane];
        float4 v1 = x4[(size_t)i1 * 32 + lane];
        float4 v2 = x4[(size_t)i2 * 32 + lane];
        float4 v3 = x4[(size_t)i3 * 32 + lane];
        float4 v4 = x4[(size_t)i4 * 32 + lane];
        float4 v5 = x4[(size_t)i5 * 32 + lane];
        float4 v6 = x4[(size_t)i6 * 32 + lane];
        float4 v7 = x4[(size_t)i7 * 32 + lane];
        sx += ((v0.x + v1.x) + (v2.x + v3.x)) + ((v4.x + v5.x) + (v6.x + v7.x));
        sy += ((v0.y + v1.y) + (v2.y + v3.y)) + ((v4.y + v5.y) + (v6.y + v7.y));
        sz += ((v0.z + v1.z) + (v2.z + v3.z)) + ((v4.z + v5.z) + (v6.z + v7.z));
        sw += ((v0.w + v1.w) + (v2.w + v3.w)) + ((v4.w + v5.w) + (v6.w + v7.w));
    }
    for (; e + 3 < endp; e += 4) {
        int i0 = cidx[e], i1 = cidx[e + 1], i2 = cidx[e + 2], i3 = cidx[e + 3];
        float4 v0 = x4[(size_t)i0 * 32 + lane];
        float4 v1 = x4[(size_t)i1 * 32 + lane];
        float4 v2 = x4[(size_t)i2 * 32 + lane];
        float4 v3 = x4[(size_t)i3 * 32 + lane];
        sx += (v0.x + v1.x) + (v2.x + v3.x);
        sy += (v0.y + v1.y) + (v2.y + v3.y);
        sz += (v0.z + v1.z) + (v2.z + v3.z);
        sw += (v0.w + v1.w) + (v2.w + v3.w);
    }
    for (; e < endp; ++e) {
        int i0 = cidx[e];
        float4 v0 = x4[(size_t)i0 * 32 + lane];
        sx += v0.x; sy += v0.y; sz += v0.z; sw += v0.w;
    }
    float inv = 1.0f / fmaxf((float)(endp - beg), 1.0f);
    float4 r;
    r.x = sx * inv; r.y = sy * inv; r.z = sz * inv; r.w = sw * inv;
    ((float4*)agg)[(size_t)node * 32 + lane] = r;
}

// ---------------- weight prep: transpose + bf16 hi/lo split ----------------
// 5 matrices (Wl0, Wr0, Wl1, Wr1, Wg1), each [128 k][128 c] fp32 ->
// dst[mat]: hi[c][k] bf16 at mat*32768, lo[c][k] at mat*32768+16384.
__global__ __launch_bounds__(256) void k_cvtw(const float* __restrict__ W0, const float* __restrict__ W1,
                                              const float* __restrict__ W2, const float* __restrict__ W3,
                                              const float* __restrict__ W4, u16* __restrict__ dst) {
    int idx = blockIdx.x * 256 + threadIdx.x;   // 5*16384
    int m = idx >> 14;
    int r = idx & 16383;
    int k = r >> 7, c = r & 127;
    const float* W = (m == 0) ? W0 : (m == 1) ? W1 : (m == 2) ? W2 : (m == 3) ? W3 : W4;
    float v = W[k * 128 + c];
    u16 h = f2bf(v);
    u16 l = f2bf(v - bf2f(h));
    u16* base = dst + (size_t)m * 32768;
    base[c * 128 + k] = h;
    base[16384 + c * 128 + k] = l;
}

// ---------------- fused SAGE layer via bf16x3 MFMA ----------------
// out = gelu(A1@W1 + b1 + A2@W2), fp32 in/out, W pre-split as WT hi/lo [c][k] bf16.
// 256 threads = 4 waves; wave = 32 nodes (2 M-tiles of 16); block = 128 nodes.
// mfma_f32_16x16x32_bf16 layouts (guide-verified m89/m92):
//   A: row = lane&15, k = 8*(lane>>4)+e (8 contiguous k)  [loaded from fp32 rows, split hi/lo]
//   B: col = lane&15, k = 8*(lane>>4)+e                   [ds_read_b128 from WT slice in LDS]
//   D: col = lane&15, row = (lane>>4)*4 + reg
// bf16x3: a.w ~= ah.wh + al.wh + ah.wl  (drops al.wl ~ 2^-18 rel).
// LDS: 4 slices [128 c][40] (32 k used + pad; stride 80B -> <=2-way banks) = 40KB.
// In-place safety (out may alias A1): wave reads/writes only its own 32 rows;
// k-loop loads precede epilogue stores (wave lockstep). Tail rows clamped/guarded.
__global__ __launch_bounds__(256) void k_sage_mf(const float* A1, const u16* __restrict__ w1hi,
                                                 const u16* __restrict__ w1lo, const float* __restrict__ b1,
                                                 const float* A2, const u16* __restrict__ w2hi,
                                                 const u16* __restrict__ w2lo, float* out) {
    __shared__ u16 lds[4][128][40];
    const int t = threadIdx.x;
    const int lane = t & 63;
    const int w = t >> 6;
    const int l15 = lane & 15;
    const int lg = lane >> 4;
    const int n0 = blockIdx.x * 128 + w * 32;
    f32x4 acc[2][8];
#pragma unroll
    for (int ti = 0; ti < 2; ++ti)
#pragma unroll
        for (int ct = 0; ct < 8; ++ct) acc[ti][ct] = (f32x4){0.f, 0.f, 0.f, 0.f};
    int nA = n0 + l15;
    int nB = n0 + 16 + l15;
    if (nA >= NN) nA = NN - 1;
    if (nB >= NN) nB = NN - 1;
    const float* a1A = A1 + (size_t)nA * 128;
    const float* a2A = A2 + (size_t)nA * 128;
    const float* a1B = A1 + (size_t)nB * 128;
    const float* a2B = A2 + (size_t)nB * 128;

    for (int k0 = 0; k0 < 128; k0 += 32) {
        __syncthreads();
        // stage 4 W-slices [128c][32k] bf16 (2 units of 64B per thread)
#pragma unroll
        for (int u = 0; u < 2; ++u) {
            int unit = t + u * 256;          // 0..511
            int s = unit >> 7, c = unit & 127;
            const u16* src = (s == 0) ? w1hi : (s == 1) ? w1lo : (s == 2) ? w2hi : w2lo;
            const uint4* s4 = (const uint4*)(src + (size_t)c * 128 + k0);
            uint4* d4 = (uint4*)&lds[s][c][0];
            d4[0] = s4[0]; d4[1] = s4[1]; d4[2] = s4[2]; d4[3] = s4[3];
        }
        __syncthreads();
        const int koff = 8 * lg;
        short8 h1A, l1A, h2A, l2A, h1B, l1B, h2B, l2B;
        cvt8(a1A + k0 + koff, h1A, l1A);
        cvt8(a2A + k0 + koff, h2A, l2A);
        cvt8(a1B + k0 + koff, h1B, l1B);
        cvt8(a2B + k0 + koff, h2B, l2B);
#pragma unroll
        for (int ct = 0; ct < 8; ++ct) {
            int c = ct * 16 + l15;
            short8 bh1 = *(const short8*)&lds[0][c][koff];
            short8 bl1 = *(const short8*)&lds[1][c][koff];
            short8 bh2 = *(const short8*)&lds[2][c][koff];
            short8 bl2 = *(const short8*)&lds[3][c][koff];
            acc[0][ct] = MFMA(h1A, bh1, acc[0][ct], 0, 0, 0);
            acc[0][ct] = MFMA(l1A, bh1, acc[0][ct], 0, 0, 0);
            acc[0][ct] = MFMA(h1A, bl1, acc[0][ct], 0, 0, 0);
            acc[0][ct] = MFMA(h2A, bh2, acc[0][ct], 0, 0, 0);
            acc[0][ct] = MFMA(l2A, bh2, acc[0][ct], 0, 0, 0);
            acc[0][ct] = MFMA(h2A, bl2, acc[0][ct], 0, 0, 0);
            acc[1][ct] = MFMA(h1B, bh1, acc[1][ct], 0, 0, 0);
            acc[1][ct] = MFMA(l1B, bh1, acc[1][ct], 0, 0, 0);
            acc[1][ct] = MFMA(h1B, bl1, acc[1][ct], 0, 0, 0);
            acc[1][ct] = MFMA(h2B, bh2, acc[1][ct], 0, 0, 0);
            acc[1][ct] = MFMA(l2B, bh2, acc[1][ct], 0, 0, 0);
            acc[1][ct] = MFMA(h2B, bl2, acc[1][ct], 0, 0, 0);
        }
    }
#pragma unroll
    for (int ti = 0; ti < 2; ++ti) {
#pragma unroll
        for (int ct = 0; ct < 8; ++ct) {
            int c = ct * 16 + l15;
            float bb = b1[c];
#pragma unroll
            for (int r = 0; r < 4; ++r) {
                int node = n0 + ti * 16 + lg * 4 + r;
                if (node < NN) out[(size_t)node * 128 + c] = gelu_f(acc[ti][ct][r] + bb);
            }
        }
    }
}

// ---------------- fused gate via bf16x3 MFMA ----------------
// gate[n] = gelu(H@Wg1 + bg1) . Wg2   (bg2 dropped: softmax shift-invariant)
__global__ __launch_bounds__(256) void k_gatef_mf(const float* __restrict__ H, const u16* __restrict__ wghi,
                                                   const u16* __restrict__ wglo, const float* __restrict__ bg1,
                                                   const float* __restrict__ Wg2, float* __restrict__ gate) {
    __shared__ u16 lds[2][128][40];
    const int t = threadIdx.x;
    const int lane = t & 63;
    const int w = t >> 6;
    const int l15 = lane & 15;
    const int lg = lane >> 4;
    const int n0 = blockIdx.x * 128 + w * 32;
    f32x4 acc[2][8];
#pragma unroll
    for (int ti = 0; ti < 2; ++ti)
#pragma unroll
        for (int ct = 0; ct < 8; ++ct) acc[ti][ct] = (f32x4){0.f, 0.f, 0.f, 0.f};
    int nA = n0 + l15;
    int nB = n0 + 16 + l15;
    if (nA >= NN) nA = NN - 1;
    if (nB >= NN) nB = NN - 1;
    const float* hA = H + (size_t)nA * 128;
    const float* hB = H + (size_t)nB * 128;

    for (int k0 = 0; k0 < 128; k0 += 32) {
        __syncthreads();
        if (t < 256) {  // 2 slices x 128 c = 256 units
            int s = t >> 7, c = t & 127;
            const u16* src = (s == 0) ? wghi : wglo;
            const uint4* s4 = (const uint4*)(src + (size_t)c * 128 + k0);
            uint4* d4 = (uint4*)&lds[s][c][0];
            d4[0] = s4[0]; d4[1] = s4[1]; d4[2] = s4[2]; d4[3] = s4[3];
        }
        __syncthreads();
        const int koff = 8 * lg;
        short8 hAh, hAl, hBh, hBl;
        cvt8(hA + k0 + koff, hAh, hAl);
        cvt8(hB + k0 + koff, hBh, hBl);
#pragma unroll
        for (int ct = 0; ct < 8; ++ct) {
            int c = ct * 16 + l15;
            short8 bh = *(const short8*)&lds[0][c][koff];
            short8 bl = *(const short8*)&lds[1][c][koff];
            acc[0][ct] = MFMA(hAh, bh, acc[0][ct], 0, 0, 0);
            acc[0][ct] = MFMA(hAl, bh, acc[0][ct], 0, 0, 0);
            acc[0][ct] = MFMA(hAh, bl, acc[0][ct], 0, 0, 0);
            acc[1][ct] = MFMA(hBh, bh, acc[1][ct], 0, 0, 0);
            acc[1][ct] = MFMA(hBl, bh, acc[1][ct], 0, 0, 0);
            acc[1][ct] = MFMA(hBh, bl, acc[1][ct], 0, 0, 0);
        }
    }
    // epilogue: p[ti][r] = sum_c gelu(acc + bg1[c]) * Wg2[c]; reduce over the 16 c-lanes
    float p[2][4];
#pragma unroll
    for (int ti = 0; ti < 2; ++ti)
#pragma unroll
        for (int r = 0; r < 4; ++r) p[ti][r] = 0.f;
#pragma unroll
    for (int ct = 0; ct < 8; ++ct) {
        int c = ct * 16 + l15;
        float bb = bg1[c];
        float gv = Wg2[c];
#pragma unroll
        for (int ti = 0; ti < 2; ++ti)
#pragma unroll
            for (int r = 0; r < 4; ++r) p[ti][r] += gelu_f(acc[ti][ct][r] + bb) * gv;
    }
#pragma unroll
    for (int m = 1; m < 16; m <<= 1) {
#pragma unroll
        for (int ti = 0; ti < 2; ++ti)
#pragma unroll
            for (int r = 0; r < 4; ++r) p[ti][r] += __shfl_xor(p[ti][r], m);
    }
    if (l15 == 0) {
#pragma unroll
        for (int ti = 0; ti < 2; ++ti)
#pragma unroll
            for (int r = 0; r < 4; ++r) {
                int node = n0 + ti * 16 + lg * 4 + r;
                if (node < NN) gate[node] = p[ti][r];
            }
    }
}

// ---------------- pooling stage 1: per-graph max + exp-sum over gate ----------------
__global__ __launch_bounds__(256) void k_pstats(const float* __restrict__ gate, const int* __restrict__ batch,
                                                float* __restrict__ gm, float* __restrict__ gden) {
    int g = blockIdx.x;
    int lo = 0, hi = NN;
    while (lo < hi) { int mid = (lo + hi) >> 1; if (batch[mid] < g) lo = mid + 1; else hi = mid; }
    int start = lo;
    lo = start; hi = NN;
    while (lo < hi) { int mid = (lo + hi) >> 1; if (batch[mid] < g + 1) lo = mid + 1; else hi = mid; }
    int endp = lo;

    __shared__ float red[256];
    int tid = threadIdx.x;

    float m = -1e30f;
    for (int i = start + tid; i < endp; i += 256) m = fmaxf(m, gate[i]);
    red[tid] = m;
    __syncthreads();
    for (int off = 128; off; off >>= 1) {
        if (tid < off) red[tid] = fmaxf(red[tid], red[tid + off]);
        __syncthreads();
    }
    m = red[0];
    __syncthreads();

    float s = 0.f;
    for (int i = start + tid; i < endp; i += 256) s += expf(gate[i] - m);
    red[tid] = s;
    __syncthreads();
    for (int off = 128; off; off >>= 1) {
        if (tid < off) red[tid] += red[tid + off];
        __syncthreads();
    }
    if (tid == 0) { gm[g] = m; gden[g] = red[0]; }
}

// ---------------- pooling stage 2: node-parallel weighted accumulate ----------------
__global__ __launch_bounds__(256) void k_pacc(const float* __restrict__ H, const float* __restrict__ gate,
                                              const int* __restrict__ batch, const float* __restrict__ gm,
                                              const float* __restrict__ gden, float* __restrict__ gacc) {
    int c = threadIdx.x & 127;
    int h = threadIdx.x >> 7;
    int n0 = blockIdx.x * 128;
    int nend = n0 + 128;
    if (nend > NN) nend = NN;
    int i = n0 + h;
    if (i >= nend) return;
    int cur = batch[i];
    float m = gm[cur], invd = 1.0f / gden[cur];
    float acc = 0.f;
    for (; i < nend; i += 2) {
        int gi = batch[i];
        if (gi != cur) {
            atomicAdd(&gacc[cur * 128 + c], acc * invd);
            acc = 0.f;
            cur = gi;
            m = gm[cur];
            invd = 1.0f / gden[cur];
        }
        acc = fmaf(expf(gate[i] - m), H[(size_t)i * 128 + c], acc);
    }
    atomicAdd(&gacc[cur * 128 + c], acc * invd);
}

// ---------------- head: out[g] = g . Wh + bh ----------------
__global__ __launch_bounds__(64) void k_head(const float* __restrict__ gacc, const float* __restrict__ Wh,
                                             const float* __restrict__ bh, float* __restrict__ out) {
    int g = blockIdx.x;
    int l = threadIdx.x;
    float v = gacc[g * 128 + l] * Wh[l] + gacc[g * 128 + 64 + l] * Wh[64 + l];
#pragma unroll
    for (int m = 1; m < 64; m <<= 1) v += __shfl_xor(v, m);
    if (l == 0) out[g] = v + bh[0];
}

extern "C" void kernel_launch(void* const* d_in, const int* in_sizes, int n_in,
                              void* d_out, int out_size, void* d_ws, size_t ws_size,
                              hipStream_t stream) {
    (void)in_sizes; (void)n_in; (void)out_size; (void)ws_size;
    const float* x   = (const float*)d_in[0];
    const int*  ei   = (const int*)d_in[1];
    const int*  batch= (const int*)d_in[2];
    const float* Wl0 = (const float*)d_in[3];
    const float* bl0 = (const float*)d_in[4];
    const float* Wr0 = (const float*)d_in[5];
    const float* Wl1 = (const float*)d_in[6];
    const float* bl1 = (const float*)d_in[7];
    const float* Wr1 = (const float*)d_in[8];
    const float* Wg1 = (const float*)d_in[9];
    const float* bg1 = (const float*)d_in[10];
    const float* Wg2 = (const float*)d_in[11];
    const float* Wh  = (const float*)d_in[13];
    const float* bh  = (const float*)d_in[14];
    float* out = (float*)d_out;

    const int* srcp = ei;
    const int* dstp = ei + NE;

    char* w = (char*)d_ws;
    size_t off = 0;
    auto alloc = [&](size_t bytes) { void* p = w + off; off += (bytes + 255) & ~(size_t)255; return p; };
    float* bufA  = (float*)alloc((size_t)NN * 128 * 4);  // agg / h2
    float* bufH  = (float*)alloc((size_t)NN * 128 * 4);  // h1
    float* gate  = (float*)alloc((size_t)NN * 4);
    int* cnt     = (int*)alloc((size_t)NN * 4);
    int* rowp    = (int*)alloc((size_t)(NN + 1) * 4);
    int* fill    = (int*)alloc((size_t)NN * 4);
    int* cidx    = (int*)alloc((size_t)NE * 4);
    int* blksum  = (int*)alloc(128 * 4);
    int* blkoff  = (int*)alloc(128 * 4);
    float* gm    = (float*)alloc(NG * 4);
    float* gden  = (float*)alloc(NG * 4);
    float* gacc  = (float*)alloc((size_t)NG * 128 * 4);
    u16* wt      = (u16*)alloc((size_t)5 * 32768 * 2);   // 5 mats x (hi|lo) [c][k] bf16

    hipMemsetAsync(cnt, 0, (size_t)NN * 4, stream);
    hipMemsetAsync(fill, 0, (size_t)NN * 4, stream);
    hipMemsetAsync(gacc, 0, (size_t)NG * 128 * 4, stream);

    // weight transpose + bf16 hi/lo split (mat order: Wl0, Wr0, Wl1, Wr1, Wg1)
    k_cvtw<<<320, 256, 0, stream>>>(Wl0, Wr0, Wl1, Wr1, Wg1, wt);

    // CSR build (reused by both layers)
    k_hist<<<(NE + 255) / 256, 256, 0, stream>>>(dstp, cnt);
    int nb = (NN + SB - 1) / SB;
    k_scan1<<<nb, SB, 0, stream>>>(cnt, rowp, blksum);
    k_scan2<<<1, 128, 0, stream>>>(blksum, blkoff, nb);
    k_scan3<<<(NN + 1 + 255) / 256, 256, 0, stream>>>(rowp, blkoff);
    k_scatter<<<(NE + 255) / 256, 256, 0, stream>>>(srcp, dstp, rowp, fill, cidx);

    int gs = (NN + 127) / 128;           // 782 MFMA-GEMM blocks (128-node tiles)
    int ga = (NN * 32 + 255) / 256;      // k_agg: 32 lanes per node
    u16* Wl0hi = wt;
    u16* Wl0lo = wt + 16384;
    u16* Wr0hi = wt + 32768;
    u16* Wr0lo = wt + 49152;
    u16* Wl1hi = wt + 65536;
    u16* Wl1lo = wt + 81920;
    u16* Wr1hi = wt + 98304;
    u16* Wr1lo = wt + 114688;
    u16* Wg1hi = wt + 131072;
    u16* Wg1lo = wt + 147456;
    // layer 0
    k_agg<<<ga, 256, 0, stream>>>(x, rowp, cidx, bufA);
    k_sage_mf<<<gs, 256, 0, stream>>>(bufA, Wl0hi, Wl0lo, bl0, x, Wr0hi, Wr0lo, bufH);    // h1
    // layer 1
    k_agg<<<ga, 256, 0, stream>>>(bufH, rowp, cidx, bufA);
    k_sage_mf<<<gs, 256, 0, stream>>>(bufA, Wl1hi, Wl1lo, bl1, bufH, Wr1hi, Wr1lo, bufA); // h2 in-place
    // gate + pool + head
    k_gatef_mf<<<gs, 256, 0, stream>>>(bufA, Wg1hi, Wg1lo, bg1, Wg2, gate);
    k_pstats<<<NG, 256, 0, stream>>>(gate, batch, gm, gden);
    k_pacc<<<(NN + 127) / 128, 256, 0, stream>>>(bufA, gate, batch, gm, gden, gacc);
    k_head<<<NG, 64, 0, stream>>>(gacc, Wh, bh, out);
}

// Round 8
// 634.330 us; speedup vs baseline: 2.6266x; 1.0473x over previous
//
#include <hip/hip_runtime.h>
#include <math.h>

#define NN 100000
#define NE 1600000
#define NG 64

typedef unsigned short u16;
typedef unsigned int u32;
typedef __attribute__((ext_vector_type(8))) short short8;   // 8 bf16 = 4 VGPR
typedef __attribute__((ext_vector_type(4))) float f32x4;    // MFMA C/D

__device__ __forceinline__ float gelu_f(float x) {
    return 0.5f * x * (1.0f + erff(x * 0.7071067811865475f));
}
// round-to-nearest-even fp32 -> bf16
__device__ __forceinline__ u16 f2bf(float f) {
    u32 u = __float_as_uint(f);
    u32 r = u + 0x7FFFu + ((u >> 16) & 1u);
    return (u16)(r >> 16);
}
__device__ __forceinline__ float bf2f(u16 h) { return __uint_as_float(((u32)h) << 16); }
// packed hi/lo bf16 pair in one u32: value ~= hi + lo, rel err ~2^-18
__device__ __forceinline__ u32 packf(float v) {
    u16 h = f2bf(v);
    u16 l = f2bf(v - bf2f(h));
    return (((u32)h) << 16) | (u32)l;
}
__device__ __forceinline__ float unpackf(u32 p) {
    return __uint_as_float(p & 0xFFFF0000u) + __uint_as_float(p << 16);
}
// 8 packed elems (2 uint4) -> hi/lo short8 for MFMA A-operand
__device__ __forceinline__ void unpack8(uint4 q0, uint4 q1, short8& hi, short8& lo) {
    u32 v[8] = {q0.x, q0.y, q0.z, q0.w, q1.x, q1.y, q1.z, q1.w};
#pragma unroll
    for (int e = 0; e < 8; ++e) {
        hi[e] = (short)(v[e] >> 16);
        lo[e] = (short)(v[e] & 0xFFFFu);
    }
}
// 8 fp32 elems (2 float4) -> hi/lo short8
__device__ __forceinline__ void cvt8f(float4 f0, float4 f1, short8& hi, short8& lo) {
    float v[8] = {f0.x, f0.y, f0.z, f0.w, f1.x, f1.y, f1.z, f1.w};
#pragma unroll
    for (int e = 0; e < 8; ++e) {
        u16 h = f2bf(v[e]);
        hi[e] = (short)h;
        lo[e] = (short)f2bf(v[e] - bf2f(h));
    }
}
#define MFMA __builtin_amdgcn_mfma_f32_16x16x32_bf16

// ---------------- CSR build ----------------
__global__ void k_hist(const int* __restrict__ dstp, int* __restrict__ cnt) {
    int e = blockIdx.x * 256 + threadIdx.x;
    if (e < NE) atomicAdd(&cnt[dstp[e]], 1);
}

#define SB 1024
__global__ __launch_bounds__(SB) void k_scan1(const int* __restrict__ cnt, int* __restrict__ rowp,
                                              int* __restrict__ blksum) {
    __shared__ int s[SB];
    int tid = threadIdx.x;
    int i = blockIdx.x * SB + tid;
    int v = (i < NN) ? cnt[i] : 0;
    int run = v;
    s[tid] = v;
    __syncthreads();
    for (int off = 1; off < SB; off <<= 1) {
        int t = (tid >= off) ? s[tid - off] : 0;
        __syncthreads();
        run += t;
        s[tid] = run;
        __syncthreads();
    }
    if (i < NN) rowp[i] = run - v;
    if (tid == SB - 1) blksum[blockIdx.x] = run;
}

__global__ void k_scan2(const int* __restrict__ blksum, int* __restrict__ blkoff, int nb) {
    __shared__ int s[128];
    int tid = threadIdx.x;
    int v = (tid < nb) ? blksum[tid] : 0;
    int run = v;
    s[tid] = v;
    __syncthreads();
    for (int off = 1; off < 128; off <<= 1) {
        int t = (tid >= off) ? s[tid - off] : 0;
        __syncthreads();
        run += t;
        s[tid] = run;
        __syncthreads();
    }
    if (tid < nb) blkoff[tid] = run - v;
}

__global__ void k_scan3(int* __restrict__ rowp, const int* __restrict__ blkoff) {
    int i = blockIdx.x * 256 + threadIdx.x;
    if (i < NN) rowp[i] += blkoff[i >> 10];
    else if (i == NN) rowp[NN] = NE;
}

__global__ void k_scatter(const int* __restrict__ srcp, const int* __restrict__ dstp,
                          const int* __restrict__ rowp, int* __restrict__ fill,
                          int* __restrict__ cidx) {
    int e = blockIdx.x * 256 + threadIdx.x;
    if (e < NE) {
        int d = dstp[e];
        int pos = atomicAdd(&fill[d], 1);
        cidx[rowp[d] + pos] = srcp[e];
    }
}

// ---------------- mean-aggregate: 32 lanes x 16B per node, 8 edges in flight ----------------
// PACKED=0: src rows are fp32 (x). PACKED=1: src rows are hi/lo-packed u32.
// Output always packed u32 (GEMM-A-ready).
template <int PACKED>
__global__ __launch_bounds__(256) void k_agg(const void* __restrict__ xin, const int* __restrict__ rowp,
                                             const int* __restrict__ cidx, u32* __restrict__ agg) {
    int tid = blockIdx.x * 256 + threadIdx.x;
    int node = tid >> 5;
    int lane = tid & 31;
    if (node >= NN) return;
    int beg = rowp[node], endp = rowp[node + 1];
    const float4* xf = (const float4*)xin;
    const uint4* xp = (const uint4*)xin;
    float sx = 0.f, sy = 0.f, sz = 0.f, sw = 0.f;
    int e = beg;
    for (; e + 7 < endp; e += 8) {
        int idx[8];
#pragma unroll
        for (int u = 0; u < 8; ++u) idx[u] = cidx[e + u];
        if (PACKED) {
            uint4 q[8];
#pragma unroll
            for (int u = 0; u < 8; ++u) q[u] = xp[(size_t)idx[u] * 32 + lane];
#pragma unroll
            for (int u = 0; u < 8; ++u) {
                sx += unpackf(q[u].x); sy += unpackf(q[u].y);
                sz += unpackf(q[u].z); sw += unpackf(q[u].w);
            }
        } else {
            float4 v[8];
#pragma unroll
            for (int u = 0; u < 8; ++u) v[u] = xf[(size_t)idx[u] * 32 + lane];
#pragma unroll
            for (int u = 0; u < 8; ++u) {
                sx += v[u].x; sy += v[u].y; sz += v[u].z; sw += v[u].w;
            }
        }
    }
    for (; e < endp; ++e) {
        int i0 = cidx[e];
        if (PACKED) {
            uint4 q = xp[(size_t)i0 * 32 + lane];
            sx += unpackf(q.x); sy += unpackf(q.y); sz += unpackf(q.z); sw += unpackf(q.w);
        } else {
            float4 v = xf[(size_t)i0 * 32 + lane];
            sx += v.x; sy += v.y; sz += v.z; sw += v.w;
        }
    }
    float inv = 1.0f / fmaxf((float)(endp - beg), 1.0f);
    uint4 o;
    o.x = packf(sx * inv); o.y = packf(sy * inv); o.z = packf(sz * inv); o.w = packf(sw * inv);
    ((uint4*)agg)[(size_t)node * 32 + lane] = o;
}

// ---------------- weight prep: transpose + bf16 hi/lo split (planes) ----------------
__global__ __launch_bounds__(256) void k_cvtw(const float* __restrict__ W0, const float* __restrict__ W1,
                                              const float* __restrict__ W2, const float* __restrict__ W3,
                                              const float* __restrict__ W4, u16* __restrict__ dst) {
    int idx = blockIdx.x * 256 + threadIdx.x;   // 5*16384
    int m = idx >> 14;
    int r = idx & 16383;
    int k = r >> 7, c = r & 127;
    const float* W = (m == 0) ? W0 : (m == 1) ? W1 : (m == 2) ? W2 : (m == 3) ? W3 : W4;
    float v = W[k * 128 + c];
    u16 h = f2bf(v);
    u16 l = f2bf(v - bf2f(h));
    u16* base = dst + (size_t)m * 32768;
    base[c * 128 + k] = h;
    base[16384 + c * 128 + k] = l;
}

// ---------------- fused SAGE layer via bf16x3 MFMA, A-prefetch pipelined ----------------
// out = gelu(A1@W1 + b1 + A2@W2); A1 packed u32; A2 fp32 (A2F32=1) or packed (0).
// Output packed u32. 256 thr = 4 waves; wave = 32 nodes (2 M-tiles); block = 128 nodes.
// A-fragments for iter kb+1 are issued before iter kb's MFMA block -> global latency
// hidden under W-stage + 96 MFMAs. Fully unrolled kb-loop -> static bank indices.
// In-place safety (out may alias A1): all A loads issue before the epilogue store of
// the owning wave; rows are wave-owned; clamped tail reads are discarded.
template <int A2F32>
__global__ __launch_bounds__(256) void k_sage_mf(const u32* A1, const u16* __restrict__ w1hi,
                                                 const u16* __restrict__ w1lo, const float* __restrict__ b1,
                                                 const void* A2v, const u16* __restrict__ w2hi,
                                                 const u16* __restrict__ w2lo, u32* out) {
    __shared__ u16 lds[4][128][40];
    const int t = threadIdx.x;
    const int lane = t & 63;
    const int w = t >> 6;
    const int l15 = lane & 15;
    const int lg = lane >> 4;
    const int n0 = blockIdx.x * 128 + w * 32;
    f32x4 acc[2][8];
#pragma unroll
    for (int ti = 0; ti < 2; ++ti)
#pragma unroll
        for (int ct = 0; ct < 8; ++ct) acc[ti][ct] = (f32x4){0.f, 0.f, 0.f, 0.f};
    int nA = n0 + l15;
    int nB = n0 + 16 + l15;
    if (nA >= NN) nA = NN - 1;
    if (nB >= NN) nB = NN - 1;
    const u32* a1A = A1 + (size_t)nA * 128;
    const u32* a1B = A1 + (size_t)nB * 128;
    const u32* a2Ap = (const u32*)A2v + (size_t)nA * 128;
    const u32* a2Bp = (const u32*)A2v + (size_t)nB * 128;
    const float* a2Af = (const float*)A2v + (size_t)nA * 128;
    const float* a2Bf = (const float*)A2v + (size_t)nB * 128;
    const int koff = 8 * lg;

    uint4 p1A[2][2], p1B[2][2];      // A1 prefetch banks (packed)
    uint4 p2A[2][2], p2B[2][2];      // A2 packed banks
    float4 f2A[2][2], f2B[2][2];     // A2 fp32 banks

    // prologue: prefetch kb=0 into bank 0
    {
        const uint4* q;
        q = (const uint4*)(a1A + koff); p1A[0][0] = q[0]; p1A[0][1] = q[1];
        q = (const uint4*)(a1B + koff); p1B[0][0] = q[0]; p1B[0][1] = q[1];
        if (A2F32) {
            const float4* f;
            f = (const float4*)(a2Af + koff); f2A[0][0] = f[0]; f2A[0][1] = f[1];
            f = (const float4*)(a2Bf + koff); f2B[0][0] = f[0]; f2B[0][1] = f[1];
        } else {
            q = (const uint4*)(a2Ap + koff); p2A[0][0] = q[0]; p2A[0][1] = q[1];
            q = (const uint4*)(a2Bp + koff); p2B[0][0] = q[0]; p2B[0][1] = q[1];
        }
    }
#pragma unroll
    for (int kb = 0; kb < 4; ++kb) {
        const int k0 = kb * 32;
        const int cur = kb & 1, nxt = cur ^ 1;
        __syncthreads();
        // stage 4 W-slices [128c][32k] bf16
#pragma unroll
        for (int u = 0; u < 2; ++u) {
            int unit = t + u * 256;
            int s = unit >> 7, c = unit & 127;
            const u16* src = (s == 0) ? w1hi : (s == 1) ? w1lo : (s == 2) ? w2hi : w2lo;
            const uint4* s4 = (const uint4*)(src + (size_t)c * 128 + k0);
            uint4* d4 = (uint4*)&lds[s][c][0];
            d4[0] = s4[0]; d4[1] = s4[1]; d4[2] = s4[2]; d4[3] = s4[3];
        }
        __syncthreads();
        // prefetch next iter's A-fragments (latency hides under MFMAs below)
        if (kb < 3) {
            const int kn = k0 + 32 + koff;
            const uint4* q;
            q = (const uint4*)(a1A + kn); p1A[nxt][0] = q[0]; p1A[nxt][1] = q[1];
            q = (const uint4*)(a1B + kn); p1B[nxt][0] = q[0]; p1B[nxt][1] = q[1];
            if (A2F32) {
                const float4* f;
                f = (const float4*)(a2Af + kn); f2A[nxt][0] = f[0]; f2A[nxt][1] = f[1];
                f = (const float4*)(a2Bf + kn); f2B[nxt][0] = f[0]; f2B[nxt][1] = f[1];
            } else {
                q = (const uint4*)(a2Ap + kn); p2A[nxt][0] = q[0]; p2A[nxt][1] = q[1];
                q = (const uint4*)(a2Bp + kn); p2B[nxt][0] = q[0]; p2B[nxt][1] = q[1];
            }
        }
        short8 h1A, l1A, h1B, l1B, h2A, l2A, h2B, l2B;
        unpack8(p1A[cur][0], p1A[cur][1], h1A, l1A);
        unpack8(p1B[cur][0], p1B[cur][1], h1B, l1B);
        if (A2F32) {
            cvt8f(f2A[cur][0], f2A[cur][1], h2A, l2A);
            cvt8f(f2B[cur][0], f2B[cur][1], h2B, l2B);
        } else {
            unpack8(p2A[cur][0], p2A[cur][1], h2A, l2A);
            unpack8(p2B[cur][0], p2B[cur][1], h2B, l2B);
        }
#pragma unroll
        for (int ct = 0; ct < 8; ++ct) {
            int c = ct * 16 + l15;
            short8 bh1 = *(const short8*)&lds[0][c][koff];
            short8 bl1 = *(const short8*)&lds[1][c][koff];
            short8 bh2 = *(const short8*)&lds[2][c][koff];
            short8 bl2 = *(const short8*)&lds[3][c][koff];
            acc[0][ct] = MFMA(h1A, bh1, acc[0][ct], 0, 0, 0);
            acc[0][ct] = MFMA(l1A, bh1, acc[0][ct], 0, 0, 0);
            acc[0][ct] = MFMA(h1A, bl1, acc[0][ct], 0, 0, 0);
            acc[0][ct] = MFMA(h2A, bh2, acc[0][ct], 0, 0, 0);
            acc[0][ct] = MFMA(l2A, bh2, acc[0][ct], 0, 0, 0);
            acc[0][ct] = MFMA(h2A, bl2, acc[0][ct], 0, 0, 0);
            acc[1][ct] = MFMA(h1B, bh1, acc[1][ct], 0, 0, 0);
            acc[1][ct] = MFMA(l1B, bh1, acc[1][ct], 0, 0, 0);
            acc[1][ct] = MFMA(h1B, bl1, acc[1][ct], 0, 0, 0);
            acc[1][ct] = MFMA(h2B, bh2, acc[1][ct], 0, 0, 0);
            acc[1][ct] = MFMA(l2B, bh2, acc[1][ct], 0, 0, 0);
            acc[1][ct] = MFMA(h2B, bl2, acc[1][ct], 0, 0, 0);
        }
    }
#pragma unroll
    for (int ti = 0; ti < 2; ++ti) {
#pragma unroll
        for (int ct = 0; ct < 8; ++ct) {
            int c = ct * 16 + l15;
            float bb = b1[c];
#pragma unroll
            for (int r = 0; r < 4; ++r) {
                int node = n0 + ti * 16 + lg * 4 + r;
                if (node < NN) out[(size_t)node * 128 + c] = packf(gelu_f(acc[ti][ct][r] + bb));
            }
        }
    }
}

// ---------------- fused gate via bf16x3 MFMA (packed H input) ----------------
__global__ __launch_bounds__(256) void k_gatef_mf(const u32* __restrict__ H, const u16* __restrict__ wghi,
                                                   const u16* __restrict__ wglo, const float* __restrict__ bg1,
                                                   const float* __restrict__ Wg2, float* __restrict__ gate) {
    __shared__ u16 lds[2][128][40];
    const int t = threadIdx.x;
    const int lane = t & 63;
    const int w = t >> 6;
    const int l15 = lane & 15;
    const int lg = lane >> 4;
    const int n0 = blockIdx.x * 128 + w * 32;
    f32x4 acc[2][8];
#pragma unroll
    for (int ti = 0; ti < 2; ++ti)
#pragma unroll
        for (int ct = 0; ct < 8; ++ct) acc[ti][ct] = (f32x4){0.f, 0.f, 0.f, 0.f};
    int nA = n0 + l15;
    int nB = n0 + 16 + l15;
    if (nA >= NN) nA = NN - 1;
    if (nB >= NN) nB = NN - 1;
    const u32* hA = H + (size_t)nA * 128;
    const u32* hB = H + (size_t)nB * 128;
    const int koff = 8 * lg;
    uint4 pA[2][2], pB[2][2];
    {
        const uint4* q;
        q = (const uint4*)(hA + koff); pA[0][0] = q[0]; pA[0][1] = q[1];
        q = (const uint4*)(hB + koff); pB[0][0] = q[0]; pB[0][1] = q[1];
    }
#pragma unroll
    for (int kb = 0; kb < 4; ++kb) {
        const int k0 = kb * 32;
        const int cur = kb & 1, nxt = cur ^ 1;
        __syncthreads();
        if (t < 256) {
            int s = t >> 7, c = t & 127;
            const u16* src = (s == 0) ? wghi : wglo;
            const uint4* s4 = (const uint4*)(src + (size_t)c * 128 + k0);
            uint4* d4 = (uint4*)&lds[s][c][0];
            d4[0] = s4[0]; d4[1] = s4[1]; d4[2] = s4[2]; d4[3] = s4[3];
        }
        __syncthreads();
        if (kb < 3) {
            const int kn = k0 + 32 + koff;
            const uint4* q;
            q = (const uint4*)(hA + kn); pA[nxt][0] = q[0]; pA[nxt][1] = q[1];
            q = (const uint4*)(hB + kn); pB[nxt][0] = q[0]; pB[nxt][1] = q[1];
        }
        short8 hAh, hAl, hBh, hBl;
        unpack8(pA[cur][0], pA[cur][1], hAh, hAl);
        unpack8(pB[cur][0], pB[cur][1], hBh, hBl);
#pragma unroll
        for (int ct = 0; ct < 8; ++ct) {
            int c = ct * 16 + l15;
            short8 bh = *(const short8*)&lds[0][c][koff];
            short8 bl = *(const short8*)&lds[1][c][koff];
            acc[0][ct] = MFMA(hAh, bh, acc[0][ct], 0, 0, 0);
            acc[0][ct] = MFMA(hAl, bh, acc[0][ct], 0, 0, 0);
            acc[0][ct] = MFMA(hAh, bl, acc[0][ct], 0, 0, 0);
            acc[1][ct] = MFMA(hBh, bh, acc[1][ct], 0, 0, 0);
            acc[1][ct] = MFMA(hBl, bh, acc[1][ct], 0, 0, 0);
            acc[1][ct] = MFMA(hBh, bl, acc[1][ct], 0, 0, 0);
        }
    }
    float p[2][4];
#pragma unroll
    for (int ti = 0; ti < 2; ++ti)
#pragma unroll
        for (int r = 0; r < 4; ++r) p[ti][r] = 0.f;
#pragma unroll
    for (int ct = 0; ct < 8; ++ct) {
        int c = ct * 16 + l15;
        float bb = bg1[c];
        float gv = Wg2[c];
#pragma unroll
        for (int ti = 0; ti < 2; ++ti)
#pragma unroll
            for (int r = 0; r < 4; ++r) p[ti][r] += gelu_f(acc[ti][ct][r] + bb) * gv;
    }
#pragma unroll
    for (int m = 1; m < 16; m <<= 1) {
#pragma unroll
        for (int ti = 0; ti < 2; ++ti)
#pragma unroll
            for (int r = 0; r < 4; ++r) p[ti][r] += __shfl_xor(p[ti][r], m);
    }
    if (l15 == 0) {
#pragma unroll
        for (int ti = 0; ti < 2; ++ti)
#pragma unroll
            for (int r = 0; r < 4; ++r) {
                int node = n0 + ti * 16 + lg * 4 + r;
                if (node < NN) gate[node] = p[ti][r];
            }
    }
}

// ---------------- pooling stage 1 ----------------
__global__ __launch_bounds__(256) void k_pstats(const float* __restrict__ gate, const int* __restrict__ batch,
                                                float* __restrict__ gm, float* __restrict__ gden) {
    int g = blockIdx.x;
    int lo = 0, hi = NN;
    while (lo < hi) { int mid = (lo + hi) >> 1; if (batch[mid] < g) lo = mid + 1; else hi = mid; }
    int start = lo;
    lo = start; hi = NN;
    while (lo < hi) { int mid = (lo + hi) >> 1; if (batch[mid] < g + 1) lo = mid + 1; else hi = mid; }
    int endp = lo;

    __shared__ float red[256];
    int tid = threadIdx.x;

    float m = -1e30f;
    for (int i = start + tid; i < endp; i += 256) m = fmaxf(m, gate[i]);
    red[tid] = m;
    __syncthreads();
    for (int off = 128; off; off >>= 1) {
        if (tid < off) red[tid] = fmaxf(red[tid], red[tid + off]);
        __syncthreads();
    }
    m = red[0];
    __syncthreads();

    float s = 0.f;
    for (int i = start + tid; i < endp; i += 256) s += expf(gate[i] - m);
    red[tid] = s;
    __syncthreads();
    for (int off = 128; off; off >>= 1) {
        if (tid < off) red[tid] += red[tid + off];
        __syncthreads();
    }
    if (tid == 0) { gm[g] = m; gden[g] = red[0]; }
}

// ---------------- pooling stage 2 (packed H) ----------------
__global__ __launch_bounds__(256) void k_pacc(const u32* __restrict__ H, const float* __restrict__ gate,
                                              const int* __restrict__ batch, const float* __restrict__ gm,
                                              const float* __restrict__ gden, float* __restrict__ gacc) {
    int c = threadIdx.x & 127;
    int h = threadIdx.x >> 7;
    int n0 = blockIdx.x * 128;
    int nend = n0 + 128;
    if (nend > NN) nend = NN;
    int i = n0 + h;
    if (i >= nend) return;
    int cur = batch[i];
    float m = gm[cur], invd = 1.0f / gden[cur];
    float acc = 0.f;
    for (; i < nend; i += 2) {
        int gi = batch[i];
        if (gi != cur) {
            atomicAdd(&gacc[cur * 128 + c], acc * invd);
            acc = 0.f;
            cur = gi;
            m = gm[cur];
            invd = 1.0f / gden[cur];
        }
        acc = fmaf(expf(gate[i] - m), unpackf(H[(size_t)i * 128 + c]), acc);
    }
    atomicAdd(&gacc[cur * 128 + c], acc * invd);
}

// ---------------- head ----------------
__global__ __launch_bounds__(64) void k_head(const float* __restrict__ gacc, const float* __restrict__ Wh,
                                             const float* __restrict__ bh, float* __restrict__ out) {
    int g = blockIdx.x;
    int l = threadIdx.x;
    float v = gacc[g * 128 + l] * Wh[l] + gacc[g * 128 + 64 + l] * Wh[64 + l];
#pragma unroll
    for (int m = 1; m < 64; m <<= 1) v += __shfl_xor(v, m);
    if (l == 0) out[g] = v + bh[0];
}

extern "C" void kernel_launch(void* const* d_in, const int* in_sizes, int n_in,
                              void* d_out, int out_size, void* d_ws, size_t ws_size,
                              hipStream_t stream) {
    (void)in_sizes; (void)n_in; (void)out_size; (void)ws_size;
    const float* x   = (const float*)d_in[0];
    const int*  ei   = (const int*)d_in[1];
    const int*  batch= (const int*)d_in[2];
    const float* Wl0 = (const float*)d_in[3];
    const float* bl0 = (const float*)d_in[4];
    const float* Wr0 = (const float*)d_in[5];
    const float* Wl1 = (const float*)d_in[6];
    const float* bl1 = (const float*)d_in[7];
    const float* Wr1 = (const float*)d_in[8];
    const float* Wg1 = (const float*)d_in[9];
    const float* bg1 = (const float*)d_in[10];
    const float* Wg2 = (const float*)d_in[11];
    const float* Wh  = (const float*)d_in[13];
    const float* bh  = (const float*)d_in[14];
    float* out = (float*)d_out;

    const int* srcp = ei;
    const int* dstp = ei + NE;

    char* w = (char*)d_ws;
    size_t off = 0;
    auto alloc = [&](size_t bytes) { void* p = w + off; off += (bytes + 255) & ~(size_t)255; return p; };
    u32* AGG   = (u32*)alloc((size_t)NN * 128 * 4);  // packed agg / h2 (in-place)
    u32* H1    = (u32*)alloc((size_t)NN * 128 * 4);  // packed h1
    float* gate  = (float*)alloc((size_t)NN * 4);
    int* cnt     = (int*)alloc((size_t)NN * 4);
    int* rowp    = (int*)alloc((size_t)(NN + 1) * 4);
    int* fill    = (int*)alloc((size_t)NN * 4);
    int* cidx    = (int*)alloc((size_t)NE * 4);
    int* blksum  = (int*)alloc(128 * 4);
    int* blkoff  = (int*)alloc(128 * 4);
    float* gm    = (float*)alloc(NG * 4);
    float* gden  = (float*)alloc(NG * 4);
    float* gacc  = (float*)alloc((size_t)NG * 128 * 4);
    u16* wt      = (u16*)alloc((size_t)5 * 32768 * 2);   // 5 mats x (hi|lo) [c][k] bf16

    hipMemsetAsync(cnt, 0, (size_t)NN * 4, stream);
    hipMemsetAsync(fill, 0, (size_t)NN * 4, stream);
    hipMemsetAsync(gacc, 0, (size_t)NG * 128 * 4, stream);

    // weight transpose + bf16 hi/lo split (mat order: Wl0, Wr0, Wl1, Wr1, Wg1)
    k_cvtw<<<320, 256, 0, stream>>>(Wl0, Wr0, Wl1, Wr1, Wg1, wt);

    // CSR build (reused by both layers)
    k_hist<<<(NE + 255) / 256, 256, 0, stream>>>(dstp, cnt);
    int nb = (NN + SB - 1) / SB;
    k_scan1<<<nb, SB, 0, stream>>>(cnt, rowp, blksum);
    k_scan2<<<1, 128, 0, stream>>>(blksum, blkoff, nb);
    k_scan3<<<(NN + 1 + 255) / 256, 256, 0, stream>>>(rowp, blkoff);
    k_scatter<<<(NE + 255) / 256, 256, 0, stream>>>(srcp, dstp, rowp, fill, cidx);

    int gs = (NN + 127) / 128;           // 782 MFMA-GEMM blocks (128-node tiles)
    int ga = (NN * 32 + 255) / 256;      // k_agg: 32 lanes per node
    u16* Wl0hi = wt;
    u16* Wl0lo = wt + 16384;
    u16* Wr0hi = wt + 32768;
    u16* Wr0lo = wt + 49152;
    u16* Wl1hi = wt + 65536;
    u16* Wl1lo = wt + 81920;
    u16* Wr1hi = wt + 98304;
    u16* Wr1lo = wt + 114688;
    u16* Wg1hi = wt + 131072;
    u16* Wg1lo = wt + 147456;
    // layer 0: agg from fp32 x; root A2 = fp32 x
    k_agg<0><<<ga, 256, 0, stream>>>(x, rowp, cidx, AGG);
    k_sage_mf<1><<<gs, 256, 0, stream>>>(AGG, Wl0hi, Wl0lo, bl0, x, Wr0hi, Wr0lo, H1);
    // layer 1: agg from packed h1; root A2 = packed h1; h2 in-place over AGG
    k_agg<1><<<ga, 256, 0, stream>>>(H1, rowp, cidx, AGG);
    k_sage_mf<0><<<gs, 256, 0, stream>>>(AGG, Wl1hi, Wl1lo, bl1, H1, Wr1hi, Wr1lo, AGG);
    // gate + pool + head (H = packed h2 in AGG)
    k_gatef_mf<<<gs, 256, 0, stream>>>(AGG, Wg1hi, Wg1lo, bg1, Wg2, gate);
    k_pstats<<<NG, 256, 0, stream>>>(gate, batch, gm, gden);
    k_pacc<<<(NN + 127) / 128, 256, 0, stream>>>(AGG, gate, batch, gm, gden, gacc);
    k_head<<<NG, 64, 0, stream>>>(gacc, Wh, bh, out);
}